// Round 1
// baseline (19482.903 us; speedup 1.0000x reference)
//
#include <hip/hip_runtime.h>
#include <math.h>

#define TOKENS 16384
#define HID 768
#define FFN_DIM 3072
#define NEXP 8
#define BM 16
#define KC 64
#define XS 772   // X LDS row stride (768+4, float4-aligned, breaks pow2 banks)
#define HS 68    // Hc LDS row stride

// ---------------- router ----------------
__global__ void __launch_bounds__(256) router_kernel(
    const float* __restrict__ x, const float* __restrict__ rw,
    const float* __restrict__ rb,
    float* __restrict__ out_rw, float* __restrict__ out_dm,
    float* __restrict__ out_logits,
    int* __restrict__ counts, float* __restrict__ probsum,
    float* __restrict__ gatesum, int* __restrict__ lists,
    float* __restrict__ glists)
{
    __shared__ float s_prob[NEXP], s_gate[NEXP];
    if (threadIdx.x < NEXP) { s_prob[threadIdx.x] = 0.f; s_gate[threadIdx.x] = 0.f; }
    __syncthreads();
    const int wave = threadIdx.x >> 6, lane = threadIdx.x & 63;
    const int t = blockIdx.x * 4 + wave;
    const float* xr = x + (size_t)t * HID;
    float acc[NEXP];
#pragma unroll
    for (int e = 0; e < NEXP; ++e) acc[e] = 0.f;
#pragma unroll
    for (int j = 0; j < 12; ++j) {
        const int i = lane + (j << 6);
        const float xv = xr[i];
        const float4 a = ((const float4*)(rw + (size_t)i * NEXP))[0];
        const float4 b = ((const float4*)(rw + (size_t)i * NEXP))[1];
        acc[0] += xv * a.x; acc[1] += xv * a.y; acc[2] += xv * a.z; acc[3] += xv * a.w;
        acc[4] += xv * b.x; acc[5] += xv * b.y; acc[6] += xv * b.z; acc[7] += xv * b.w;
    }
#pragma unroll
    for (int off = 32; off > 0; off >>= 1)
#pragma unroll
        for (int e = 0; e < NEXP; ++e) acc[e] += __shfl_down(acc[e], off, 64);

    if (lane == 0) {
        float lg[NEXP];
        float m = -1e30f;
#pragma unroll
        for (int e = 0; e < NEXP; ++e) { lg[e] = acc[e] + rb[e]; m = fmaxf(m, lg[e]); }
        float ex[NEXP]; float s = 0.f;
#pragma unroll
        for (int e = 0; e < NEXP; ++e) { ex[e] = expf(lg[e] - m); s += ex[e]; }
        const float inv = 1.f / s;
        float* lrow = out_logits + (size_t)t * NEXP;
        float* prow = out_rw + (size_t)t * NEXP;
#pragma unroll
        for (int e = 0; e < NEXP; ++e) {
            lrow[e] = lg[e];
            const float p = ex[e] * inv;
            prow[e] = p;
            atomicAdd(&s_prob[e], p);
        }
        // top-2 (strict > keeps earliest index on ties, matching lax.top_k)
        int i1 = 0;
#pragma unroll
        for (int e = 1; e < NEXP; ++e) if (lg[e] > lg[i1]) i1 = e;
        int i2 = (i1 == 0) ? 1 : 0;
#pragma unroll
        for (int e = 0; e < NEXP; ++e) if (e != i1 && lg[e] > lg[i2]) i2 = e;
        const float e2 = expf(lg[i2] - lg[i1]);
        const float g1 = 1.f / (1.f + e2);
        const float g2 = e2 / (1.f + e2);
        out_dm[(size_t)t * NEXP + i1] = g1;
        out_dm[(size_t)t * NEXP + i2] = g2;
        atomicAdd(&s_gate[i1], g1);
        atomicAdd(&s_gate[i2], g2);
        const int s1 = atomicAdd(&counts[i1], 1);
        lists[i1 * TOKENS + s1] = t; glists[i1 * TOKENS + s1] = g1;
        const int s2 = atomicAdd(&counts[i2], 1);
        lists[i2 * TOKENS + s2] = t; glists[i2 * TOKENS + s2] = g2;
    }
    __syncthreads();
    if (threadIdx.x < NEXP) {
        atomicAdd(&probsum[threadIdx.x], s_prob[threadIdx.x]);
        atomicAdd(&gatesum[threadIdx.x], s_gate[threadIdx.x]);
    }
}

// ---------------- aux loss ----------------
__global__ void aux_kernel(const float* __restrict__ probsum,
                           const float* __restrict__ gatesum,
                           float* __restrict__ out_aux)
{
    if (threadIdx.x == 0 && blockIdx.x == 0) {
        float s = 0.f;
        for (int e = 0; e < NEXP; ++e)
            s += (probsum[e] / (float)TOKENS) * (gatesum[e] / (float)TOKENS);
        *out_aux = s * (float)NEXP;
    }
}

// ---------------- fused expert FFN ----------------
__device__ __forceinline__ float gelu_tanh(float v) {
    // jax.nn.gelu default approximate=True
    return 0.5f * v * (1.f + tanhf(0.7978845608028654f * (v + 0.044715f * v * v * v)));
}

__global__ void __launch_bounds__(256) ffn_kernel(
    const float* __restrict__ x, const float* __restrict__ w1,
    const float* __restrict__ b1, const float* __restrict__ w2,
    const float* __restrict__ b2, const int* __restrict__ counts,
    const int* __restrict__ lists, const float* __restrict__ glists,
    float* __restrict__ out)
{
    const int e = blockIdx.y;
    const int count = counts[e];
    const int row0 = blockIdx.x * BM;
    if (row0 >= count) return;

    __shared__ float sX[BM * XS];
    __shared__ float sH[BM * HS];
    __shared__ int sTok[BM];
    __shared__ float sGate[BM];
    const int tid = threadIdx.x;

    if (tid < BM) {
        const int ri = row0 + tid;
        int tok = 0; float g = 0.f;
        if (ri < count) { tok = lists[e * TOKENS + ri]; g = glists[e * TOKENS + ri]; }
        sTok[tid] = tok; sGate[tid] = g;
    }
    __syncthreads();
    // stage X tile [BM x 768] into LDS (16 threads/row x 12 float4)
    {
        const int r = tid >> 4, q = tid & 15;
        const float4* src = (const float4*)(x + (size_t)sTok[r] * HID);
#pragma unroll
        for (int j = 0; j < 12; ++j) {
            const float4 v = src[q + (j << 4)];
            *(float4*)&sX[r * XS + ((q + (j << 4)) << 2)] = v;
        }
    }
    __syncthreads();

    const float* w1e = w1 + (size_t)e * HID * FFN_DIM;
    const float* w2e = w2 + (size_t)e * FFN_DIM * HID;
    const float* b1e = b1 + (size_t)e * FFN_DIM;
    const float* b2e = b2 + (size_t)e * HID;
    const int r1 = tid & 15;           // my row (both phases)
    const int c0 = (tid >> 4) << 2;    // phase-1: 4 cols within chunk
    const int c2 = (tid >> 4) * 48;    // phase-2: 48 cols within HIDDEN

    float Y[48];
#pragma unroll
    for (int j = 0; j < 48; ++j) Y[j] = 0.f;

    for (int ch = 0; ch < FFN_DIM / KC; ++ch) {
        // phase 1: Hc[r1][c0..c0+3] = gelu(X @ W1[:, chunk] + b1)
        float h0 = 0.f, h1 = 0.f, h2 = 0.f, h3 = 0.f;
        const float* w1c = w1e + ch * KC + c0;
        for (int i = 0; i < HID; i += 4) {
            const float4 xv = *(const float4*)&sX[r1 * XS + i];
            const float* wp = w1c + (size_t)i * FFN_DIM;
            const float4 wa = *(const float4*)(wp);
            const float4 wb = *(const float4*)(wp + FFN_DIM);
            const float4 wc = *(const float4*)(wp + 2 * FFN_DIM);
            const float4 wd = *(const float4*)(wp + 3 * FFN_DIM);
            h0 += xv.x * wa.x + xv.y * wb.x + xv.z * wc.x + xv.w * wd.x;
            h1 += xv.x * wa.y + xv.y * wb.y + xv.z * wc.y + xv.w * wd.y;
            h2 += xv.x * wa.z + xv.y * wb.z + xv.z * wc.z + xv.w * wd.z;
            h3 += xv.x * wa.w + xv.y * wb.w + xv.z * wc.w + xv.w * wd.w;
        }
        const int cb = ch * KC + c0;
        h0 = gelu_tanh(h0 + b1e[cb + 0]);
        h1 = gelu_tanh(h1 + b1e[cb + 1]);
        h2 = gelu_tanh(h2 + b1e[cb + 2]);
        h3 = gelu_tanh(h3 + b1e[cb + 3]);
        __syncthreads();   // previous chunk's sH readers done
        *(float4*)&sH[r1 * HS + c0] = make_float4(h0, h1, h2, h3);
        __syncthreads();
        // phase 2: Y[c2..c2+47] += Hc @ W2[chunk, :]
        const float* w2c = w2e + (size_t)ch * KC * HID + c2;
        for (int k = 0; k < KC; ++k) {
            const float hv = sH[r1 * HS + k];
            const float4* wr = (const float4*)(w2c + (size_t)k * HID);
#pragma unroll
            for (int j4 = 0; j4 < 12; ++j4) {
                const float4 w = wr[j4];
                Y[j4 * 4 + 0] += hv * w.x;
                Y[j4 * 4 + 1] += hv * w.y;
                Y[j4 * 4 + 2] += hv * w.z;
                Y[j4 * 4 + 3] += hv * w.w;
            }
        }
    }
    // scatter: combined[tok] += gate * (Y + b2)
    const int ri = row0 + r1;
    if (ri < count) {
        const float g = sGate[r1];
        float* orow = out + (size_t)sTok[r1] * HID + c2;
#pragma unroll
        for (int j = 0; j < 48; ++j)
            atomicAdd(&orow[j], g * (Y[j] + b2e[c2 + j]));
    }
}

extern "C" void kernel_launch(void* const* d_in, const int* in_sizes, int n_in,
                              void* d_out, int out_size, void* d_ws, size_t ws_size,
                              hipStream_t stream)
{
    const float* x  = (const float*)d_in[0];
    const float* rw = (const float*)d_in[1];
    const float* rb = (const float*)d_in[2];
    const float* w1 = (const float*)d_in[3];
    const float* b1 = (const float*)d_in[4];
    const float* w2 = (const float*)d_in[5];
    const float* b2 = (const float*)d_in[6];

    float* out = (float*)d_out;
    float* out_comb   = out;                                   // [T,768]
    float* out_rw     = out + (size_t)TOKENS * HID;            // [T,8]
    float* out_dm     = out_rw + (size_t)TOKENS * NEXP;        // [T,8]
    float* out_aux    = out_dm + (size_t)TOKENS * NEXP;        // [1]
    float* out_logits = out_aux + 1;                           // [T,8]

    char* ws = (char*)d_ws;
    int*   counts  = (int*)ws;                                  // 8 ints
    float* probsum = (float*)(ws + 64);                         // 8 f32
    float* gatesum = (float*)(ws + 96);                         // 8 f32
    int*   lists   = (int*)(ws + 128);                          // 8*T ints
    float* glists  = (float*)(ws + 128 + (size_t)NEXP * TOKENS * 4);

    // zero combined + dispatch_mask (poisoned 0xAA) and the ws accumulators
    hipMemsetAsync(d_out, 0, (size_t)out_size * sizeof(float), stream);
    hipMemsetAsync(d_ws, 0, 128, stream);

    router_kernel<<<dim3(TOKENS / 4), 256, 0, stream>>>(
        x, rw, rb, out_rw, out_dm, out_logits,
        counts, probsum, gatesum, lists, glists);
    aux_kernel<<<1, 64, 0, stream>>>(probsum, gatesum, out_aux);
    ffn_kernel<<<dim3(TOKENS / BM, NEXP), 256, 0, stream>>>(
        x, w1, b1, w2, b2, counts, lists, glists, out_comb);
}

// Round 2
// 19434.920 us; speedup vs baseline: 1.0025x; 1.0025x over previous
//
#include <hip/hip_runtime.h>
#include <math.h>

#define TOKENS 16384
#define HID 768
#define FFN_DIM 3072
#define NEXP 8

typedef __bf16 bf16x8 __attribute__((ext_vector_type(8)));
typedef float f32x4 __attribute__((ext_vector_type(4)));

#define GLOBAL_AS(p) ((const __attribute__((address_space(1))) void*)(p))
#define LDS_AS(p)    ((__attribute__((address_space(3))) void*)(p))

__device__ __forceinline__ float gelu_f(float x) {
    const float x3 = x * x * x;
    const float z = 0.7978845608028654f * (x + 0.044715f * x3);
    const float e = __expf(2.f * z);
    const float t = 1.f - 2.f / (e + 1.f);   // tanh(z), saturates safely at +/-1
    return 0.5f * x * (1.f + t);
}

__device__ __forceinline__ unsigned short f2bf(float v) {
    return __builtin_bit_cast(unsigned short, (__bf16)v);
}

// ---------------- router ----------------
__global__ void __launch_bounds__(256) router_kernel(
    const float* __restrict__ x, const float* __restrict__ rw,
    const float* __restrict__ rb,
    float* __restrict__ out_rw, float* __restrict__ out_dm,
    float* __restrict__ out_logits,
    int* __restrict__ counts, float* __restrict__ probsum,
    float* __restrict__ gatesum, int* __restrict__ lists,
    float* __restrict__ glists)
{
    __shared__ float s_prob[NEXP], s_gate[NEXP];
    if (threadIdx.x < NEXP) { s_prob[threadIdx.x] = 0.f; s_gate[threadIdx.x] = 0.f; }
    __syncthreads();
    const int wave = threadIdx.x >> 6, lane = threadIdx.x & 63;
    const int t = blockIdx.x * 4 + wave;
    const float* xr = x + (size_t)t * HID;
    float acc[NEXP];
#pragma unroll
    for (int e = 0; e < NEXP; ++e) acc[e] = 0.f;
#pragma unroll
    for (int j = 0; j < 12; ++j) {
        const int i = lane + (j << 6);
        const float xv = xr[i];
        const float4 a = ((const float4*)(rw + (size_t)i * NEXP))[0];
        const float4 b = ((const float4*)(rw + (size_t)i * NEXP))[1];
        acc[0] += xv * a.x; acc[1] += xv * a.y; acc[2] += xv * a.z; acc[3] += xv * a.w;
        acc[4] += xv * b.x; acc[5] += xv * b.y; acc[6] += xv * b.z; acc[7] += xv * b.w;
    }
#pragma unroll
    for (int off = 32; off > 0; off >>= 1)
#pragma unroll
        for (int e = 0; e < NEXP; ++e) acc[e] += __shfl_down(acc[e], off, 64);

    if (lane == 0) {
        float lg[NEXP];
        float m = -1e30f;
#pragma unroll
        for (int e = 0; e < NEXP; ++e) { lg[e] = acc[e] + rb[e]; m = fmaxf(m, lg[e]); }
        float ex[NEXP]; float s = 0.f;
#pragma unroll
        for (int e = 0; e < NEXP; ++e) { ex[e] = expf(lg[e] - m); s += ex[e]; }
        const float inv = 1.f / s;
        float* lrow = out_logits + (size_t)t * NEXP;
        float* prow = out_rw + (size_t)t * NEXP;
#pragma unroll
        for (int e = 0; e < NEXP; ++e) {
            lrow[e] = lg[e];
            const float p = ex[e] * inv;
            prow[e] = p;
            atomicAdd(&s_prob[e], p);
        }
        int i1 = 0;
#pragma unroll
        for (int e = 1; e < NEXP; ++e) if (lg[e] > lg[i1]) i1 = e;
        int i2 = (i1 == 0) ? 1 : 0;
#pragma unroll
        for (int e = 0; e < NEXP; ++e) if (e != i1 && lg[e] > lg[i2]) i2 = e;
        const float e2 = expf(lg[i2] - lg[i1]);
        const float g1 = 1.f / (1.f + e2);
        const float g2 = e2 / (1.f + e2);
        out_dm[(size_t)t * NEXP + i1] = g1;
        out_dm[(size_t)t * NEXP + i2] = g2;
        atomicAdd(&s_gate[i1], g1);
        atomicAdd(&s_gate[i2], g2);
        const int s1 = atomicAdd(&counts[i1], 1);
        lists[i1 * TOKENS + s1] = t; glists[i1 * TOKENS + s1] = g1;
        const int s2 = atomicAdd(&counts[i2], 1);
        lists[i2 * TOKENS + s2] = t; glists[i2 * TOKENS + s2] = g2;
    }
    __syncthreads();
    if (threadIdx.x < NEXP) {
        atomicAdd(&probsum[threadIdx.x], s_prob[threadIdx.x]);
        atomicAdd(&gatesum[threadIdx.x], s_gate[threadIdx.x]);
    }
}

// ---------------- finalize: aux loss + segment offsets ----------------
__global__ void finalize_kernel(const int* __restrict__ counts,
                                const float* __restrict__ probsum,
                                const float* __restrict__ gatesum,
                                int* __restrict__ offs,
                                float* __restrict__ out_aux)
{
    if (threadIdx.x == 0 && blockIdx.x == 0) {
        float s = 0.f; int off = 0;
        for (int e = 0; e < NEXP; ++e) {
            offs[e] = off; off += counts[e];
            s += (probsum[e] / (float)TOKENS) * (gatesum[e] / (float)TOKENS);
        }
        *out_aux = s * (float)NEXP;
    }
}

// ---------------- conversions ----------------
// x fp32 [T,HID] -> bf16
__global__ void __launch_bounds__(256) convx_kernel(const float* __restrict__ x,
                                                    unsigned short* __restrict__ xb)
{
    const int i = blockIdx.x * 256 + threadIdx.x;
    const float4 v = ((const float4*)x)[i];
    uint2 o;
    o.x = (unsigned)f2bf(v.x) | ((unsigned)f2bf(v.y) << 16);
    o.y = (unsigned)f2bf(v.z) | ((unsigned)f2bf(v.w) << 16);
    ((uint2*)xb)[i] = o;
}

// fp32 [E][R][C] -> bf16 transposed [E][C][R]
__global__ void __launch_bounds__(256) convT_kernel(const float* __restrict__ in,
                                                    unsigned short* __restrict__ out,
                                                    int R, int C)
{
    __shared__ float sT[32][65];  // sT[c][r]
    const int e = blockIdx.z;
    const float* in_e = in + (size_t)e * R * C;
    unsigned short* out_e = out + (size_t)e * R * C;
    const int r0 = blockIdx.y * 64;
    const int c0 = blockIdx.x * 32;
    const int tid = threadIdx.x;
    const int rr = tid >> 3, c4 = (tid & 7) * 4;
#pragma unroll
    for (int half = 0; half < 2; ++half) {
        const int r = rr + half * 32;
        const float4 v = *(const float4*)&in_e[(size_t)(r0 + r) * C + c0 + c4];
        sT[c4 + 0][r] = v.x; sT[c4 + 1][r] = v.y;
        sT[c4 + 2][r] = v.z; sT[c4 + 3][r] = v.w;
    }
    __syncthreads();
    const int c = tid >> 3, u = tid & 7;
    uint4 pk;
    const float* sr = &sT[c][u * 8];
    pk.x = (unsigned)f2bf(sr[0]) | ((unsigned)f2bf(sr[1]) << 16);
    pk.y = (unsigned)f2bf(sr[2]) | ((unsigned)f2bf(sr[3]) << 16);
    pk.z = (unsigned)f2bf(sr[4]) | ((unsigned)f2bf(sr[5]) << 16);
    pk.w = (unsigned)f2bf(sr[6]) | ((unsigned)f2bf(sr[7]) << 16);
    *(uint4*)&out_e[(size_t)(c0 + c) * R + r0 + u * 8] = pk;
}

// ---------------- GEMM1: H = gelu(Xg @ W1 + b1), bf16 out ----------------
__global__ void __launch_bounds__(256) gemm1_kernel(
    const unsigned short* __restrict__ Xb, const unsigned short* __restrict__ W1T,
    const float* __restrict__ b1, const int* __restrict__ counts,
    const int* __restrict__ offs, const int* __restrict__ lists,
    unsigned short* __restrict__ H)
{
    const int e = blockIdx.z;
    const int cnt = counts[e];
    const int m0 = blockIdx.y * 128;
    if (m0 >= cnt) return;
    const int n0 = blockIdx.x * 128;
    const int seg = offs[e];

    __shared__ __bf16 sA[128 * 64];
    __shared__ __bf16 sB[128 * 64];
    __shared__ int sTok[128];

    const int tid = threadIdx.x;
    const int w = tid >> 6, lane = tid & 63;
    if (tid < 128) {
        int ri = m0 + tid; if (ri >= cnt) ri = cnt - 1;
        sTok[tid] = lists[e * TOKENS + ri];
    }
    __syncthreads();

    const unsigned short* w1e = W1T + (size_t)e * (FFN_DIM * HID);
    const int lr = lane >> 3;         // row within 8-row group
    const int lk = (lane & 7) * 8;    // k elem offset within 64
    const unsigned short* aPtr[4];
    const unsigned short* bPtr[4];
    __bf16* ldsA[4];
    __bf16* ldsB[4];
#pragma unroll
    for (int j = 0; j < 4; ++j) {
        const int row = (w * 4 + j) * 8 + lr;
        aPtr[j] = Xb + (size_t)sTok[row] * HID + lk;
        bPtr[j] = w1e + (size_t)(n0 + row) * HID + lk;
        ldsA[j] = sA + (w * 4 + j) * 512;
        ldsB[j] = sB + (w * 4 + j) * 512;
    }

    f32x4 acc[4][4];
#pragma unroll
    for (int a = 0; a < 4; ++a)
#pragma unroll
        for (int b = 0; b < 4; ++b) acc[a][b] = (f32x4)(0.f);

    const int wm = (w >> 1) * 64, wn = (w & 1) * 64;
    const int fr = lane & 15;
    const int fk = (lane >> 4) * 8;

    for (int kt = 0; kt < HID / 64; ++kt) {
        const int k0 = kt * 64;
#pragma unroll
        for (int j = 0; j < 4; ++j) {
            __builtin_amdgcn_global_load_lds(GLOBAL_AS(aPtr[j] + k0), LDS_AS(ldsA[j]), 16, 0, 0);
            __builtin_amdgcn_global_load_lds(GLOBAL_AS(bPtr[j] + k0), LDS_AS(ldsB[j]), 16, 0, 0);
        }
        __syncthreads();
#pragma unroll
        for (int kk = 0; kk < 64; kk += 32) {
            bf16x8 af[4], bb[4];
#pragma unroll
            for (int t = 0; t < 4; ++t) {
                af[t] = *(const bf16x8*)&sA[(wm + t * 16 + fr) * 64 + kk + fk];
                bb[t] = *(const bf16x8*)&sB[(wn + t * 16 + fr) * 64 + kk + fk];
            }
#pragma unroll
            for (int tm = 0; tm < 4; ++tm)
#pragma unroll
                for (int tn = 0; tn < 4; ++tn)
                    acc[tm][tn] = __builtin_amdgcn_mfma_f32_16x16x32_bf16(
                        af[tm], bb[tn], acc[tm][tn], 0, 0, 0);
        }
        __syncthreads();
    }

    const float* b1e = b1 + (size_t)e * FFN_DIM;
    float bias[4];
#pragma unroll
    for (int tn = 0; tn < 4; ++tn) bias[tn] = b1e[n0 + wn + tn * 16 + fr];
#pragma unroll
    for (int tm = 0; tm < 4; ++tm) {
#pragma unroll
        for (int tn = 0; tn < 4; ++tn) {
            const int n = n0 + wn + tn * 16 + fr;
#pragma unroll
            for (int r = 0; r < 4; ++r) {
                const int m = m0 + wm + tm * 16 + (lane >> 4) * 4 + r;
                if (m < cnt) {
                    const float h = gelu_f(acc[tm][tn][r] + bias[tn]);
                    H[(size_t)(seg + m) * FFN_DIM + n] = f2bf(h);
                }
            }
        }
    }
}

// ---------------- GEMM2: out[tok] += gate*(H @ W2 + b2) ----------------
__global__ void __launch_bounds__(256) gemm2_kernel(
    const unsigned short* __restrict__ H, const unsigned short* __restrict__ W2T,
    const float* __restrict__ b2, const int* __restrict__ counts,
    const int* __restrict__ offs, const int* __restrict__ lists,
    const float* __restrict__ glists, float* __restrict__ out)
{
    const int e = blockIdx.z;
    const int cnt = counts[e];
    const int m0 = blockIdx.y * 128;
    if (m0 >= cnt) return;
    const int n0 = blockIdx.x * 128;
    const int seg = offs[e];

    __shared__ __bf16 sA[128 * 64];
    __shared__ __bf16 sB[128 * 64];
    __shared__ int sTok[128];
    __shared__ float sGate[128];

    const int tid = threadIdx.x;
    const int w = tid >> 6, lane = tid & 63;
    if (tid < 128) {
        int ri = m0 + tid; if (ri >= cnt) ri = cnt - 1;
        sTok[tid] = lists[e * TOKENS + ri];
        sGate[tid] = glists[e * TOKENS + ri];
    }
    __syncthreads();

    const unsigned short* w2e = W2T + (size_t)e * (FFN_DIM * HID);
    const int lr = lane >> 3;
    const int lk = (lane & 7) * 8;
    const unsigned short* aPtr[4];
    const unsigned short* bPtr[4];
    __bf16* ldsA[4];
    __bf16* ldsB[4];
#pragma unroll
    for (int j = 0; j < 4; ++j) {
        const int row = (w * 4 + j) * 8 + lr;
        aPtr[j] = H + (size_t)(seg + m0 + row) * FFN_DIM + lk;
        bPtr[j] = w2e + (size_t)(n0 + row) * FFN_DIM + lk;
        ldsA[j] = sA + (w * 4 + j) * 512;
        ldsB[j] = sB + (w * 4 + j) * 512;
    }

    f32x4 acc[4][4];
#pragma unroll
    for (int a = 0; a < 4; ++a)
#pragma unroll
        for (int b = 0; b < 4; ++b) acc[a][b] = (f32x4)(0.f);

    const int wm = (w >> 1) * 64, wn = (w & 1) * 64;
    const int fr = lane & 15;
    const int fk = (lane >> 4) * 8;

    for (int kt = 0; kt < FFN_DIM / 64; ++kt) {
        const int k0 = kt * 64;
#pragma unroll
        for (int j = 0; j < 4; ++j) {
            __builtin_amdgcn_global_load_lds(GLOBAL_AS(aPtr[j] + k0), LDS_AS(ldsA[j]), 16, 0, 0);
            __builtin_amdgcn_global_load_lds(GLOBAL_AS(bPtr[j] + k0), LDS_AS(ldsB[j]), 16, 0, 0);
        }
        __syncthreads();
#pragma unroll
        for (int kk = 0; kk < 64; kk += 32) {
            bf16x8 af[4], bb[4];
#pragma unroll
            for (int t = 0; t < 4; ++t) {
                af[t] = *(const bf16x8*)&sA[(wm + t * 16 + fr) * 64 + kk + fk];
                bb[t] = *(const bf16x8*)&sB[(wn + t * 16 + fr) * 64 + kk + fk];
            }
#pragma unroll
            for (int tm = 0; tm < 4; ++tm)
#pragma unroll
                for (int tn = 0; tn < 4; ++tn)
                    acc[tm][tn] = __builtin_amdgcn_mfma_f32_16x16x32_bf16(
                        af[tm], bb[tn], acc[tm][tn], 0, 0, 0);
        }
        __syncthreads();
    }

    const float* b2e = b2 + (size_t)e * HID;
    float bias[4];
#pragma unroll
    for (int tn = 0; tn < 4; ++tn) bias[tn] = b2e[n0 + wn + tn * 16 + fr];
#pragma unroll
    for (int tm = 0; tm < 4; ++tm) {
#pragma unroll
        for (int tn = 0; tn < 4; ++tn) {
            const int n = n0 + wn + tn * 16 + fr;
#pragma unroll
            for (int r = 0; r < 4; ++r) {
                const int rloc = wm + tm * 16 + (lane >> 4) * 4 + r;
                const int m = m0 + rloc;
                if (m < cnt) {
                    const float y = acc[tm][tn][r] + bias[tn];
                    atomicAdd(&out[(size_t)sTok[rloc] * HID + n], sGate[rloc] * y);
                }
            }
        }
    }
}

// ---------------- fallback fp32 FFN (round-1 path, used if ws too small) ----------------
#define BM 16
#define KC 64
#define XS 772
#define HS 68
__global__ void __launch_bounds__(256) ffn_kernel(
    const float* __restrict__ x, const float* __restrict__ w1,
    const float* __restrict__ b1, const float* __restrict__ w2,
    const float* __restrict__ b2, const int* __restrict__ counts,
    const int* __restrict__ lists, const float* __restrict__ glists,
    float* __restrict__ out)
{
    const int e = blockIdx.y;
    const int count = counts[e];
    const int row0 = blockIdx.x * BM;
    if (row0 >= count) return;

    __shared__ float sX[BM * XS];
    __shared__ float sH[BM * HS];
    __shared__ int sTokF[BM];
    __shared__ float sGateF[BM];
    const int tid = threadIdx.x;

    if (tid < BM) {
        const int ri = row0 + tid;
        int tok = 0; float g = 0.f;
        if (ri < count) { tok = lists[e * TOKENS + ri]; g = glists[e * TOKENS + ri]; }
        sTokF[tid] = tok; sGateF[tid] = g;
    }
    __syncthreads();
    {
        const int r = tid >> 4, q = tid & 15;
        const float4* src = (const float4*)(x + (size_t)sTokF[r] * HID);
#pragma unroll
        for (int j = 0; j < 12; ++j) {
            const float4 v = src[q + (j << 4)];
            *(float4*)&sX[r * XS + ((q + (j << 4)) << 2)] = v;
        }
    }
    __syncthreads();

    const float* w1e = w1 + (size_t)e * HID * FFN_DIM;
    const float* w2e = w2 + (size_t)e * FFN_DIM * HID;
    const float* b1e = b1 + (size_t)e * FFN_DIM;
    const float* b2e = b2 + (size_t)e * HID;
    const int r1 = tid & 15;
    const int c0 = (tid >> 4) << 2;
    const int c2 = (tid >> 4) * 48;

    float Y[48];
#pragma unroll
    for (int j = 0; j < 48; ++j) Y[j] = 0.f;

    for (int ch = 0; ch < FFN_DIM / KC; ++ch) {
        float h0 = 0.f, h1 = 0.f, h2 = 0.f, h3 = 0.f;
        const float* w1c = w1e + ch * KC + c0;
        for (int i = 0; i < HID; i += 4) {
            const float4 xv = *(const float4*)&sX[r1 * XS + i];
            const float* wp = w1c + (size_t)i * FFN_DIM;
            const float4 wa = *(const float4*)(wp);
            const float4 wb = *(const float4*)(wp + FFN_DIM);
            const float4 wc = *(const float4*)(wp + 2 * FFN_DIM);
            const float4 wd = *(const float4*)(wp + 3 * FFN_DIM);
            h0 += xv.x * wa.x + xv.y * wb.x + xv.z * wc.x + xv.w * wd.x;
            h1 += xv.x * wa.y + xv.y * wb.y + xv.z * wc.y + xv.w * wd.y;
            h2 += xv.x * wa.z + xv.y * wb.z + xv.z * wc.z + xv.w * wd.z;
            h3 += xv.x * wa.w + xv.y * wb.w + xv.z * wc.w + xv.w * wd.w;
        }
        const int cb = ch * KC + c0;
        h0 = gelu_f(h0 + b1e[cb + 0]);
        h1 = gelu_f(h1 + b1e[cb + 1]);
        h2 = gelu_f(h2 + b1e[cb + 2]);
        h3 = gelu_f(h3 + b1e[cb + 3]);
        __syncthreads();
        *(float4*)&sH[r1 * HS + c0] = make_float4(h0, h1, h2, h3);
        __syncthreads();
        const float* w2c = w2e + (size_t)ch * KC * HID + c2;
        for (int k = 0; k < KC; ++k) {
            const float hv = sH[r1 * HS + k];
            const float4* wr = (const float4*)(w2c + (size_t)k * HID);
#pragma unroll
            for (int j4 = 0; j4 < 12; ++j4) {
                const float4 wv = wr[j4];
                Y[j4 * 4 + 0] += hv * wv.x;
                Y[j4 * 4 + 1] += hv * wv.y;
                Y[j4 * 4 + 2] += hv * wv.z;
                Y[j4 * 4 + 3] += hv * wv.w;
            }
        }
    }
    const int ri = row0 + r1;
    if (ri < count) {
        const float g = sGateF[r1];
        float* orow = out + (size_t)sTokF[r1] * HID + c2;
#pragma unroll
        for (int j = 0; j < 48; ++j)
            atomicAdd(&orow[j], g * (Y[j] + b2e[c2 + j]));
    }
}

extern "C" void kernel_launch(void* const* d_in, const int* in_sizes, int n_in,
                              void* d_out, int out_size, void* d_ws, size_t ws_size,
                              hipStream_t stream)
{
    const float* x  = (const float*)d_in[0];
    const float* rw = (const float*)d_in[1];
    const float* rb = (const float*)d_in[2];
    const float* w1 = (const float*)d_in[3];
    const float* b1 = (const float*)d_in[4];
    const float* w2 = (const float*)d_in[5];
    const float* b2 = (const float*)d_in[6];

    float* out = (float*)d_out;
    float* out_comb   = out;
    float* out_rw     = out + (size_t)TOKENS * HID;
    float* out_dm     = out_rw + (size_t)TOKENS * NEXP;
    float* out_aux    = out_dm + (size_t)TOKENS * NEXP;
    float* out_logits = out_aux + 1;

    char* ws = (char*)d_ws;
    int*   counts  = (int*)ws;                        // [0,32)
    int*   offs    = (int*)(ws + 32);                 // [32,64)
    float* probsum = (float*)(ws + 64);               // [64,96)
    float* gatesum = (float*)(ws + 96);               // [96,128)
    int*   lists   = (int*)(ws + 128);
    float* glists  = (float*)(ws + 128 + (size_t)NEXP * TOKENS * 4);
    size_t off = 128 + (size_t)NEXP * TOKENS * 8;
    off = (off + 255) & ~(size_t)255;
    unsigned short* Xb  = (unsigned short*)(ws + off); off += (size_t)TOKENS * HID * 2;
    unsigned short* W1T = (unsigned short*)(ws + off); off += (size_t)NEXP * HID * FFN_DIM * 2;
    unsigned short* W2T = (unsigned short*)(ws + off); off += (size_t)NEXP * HID * FFN_DIM * 2;
    unsigned short* Hbuf= (unsigned short*)(ws + off); off += (size_t)(2 * TOKENS + 128) * FFN_DIM * 2;
    const size_t need = off;

    hipMemsetAsync(d_out, 0, (size_t)out_size * sizeof(float), stream);
    hipMemsetAsync(d_ws, 0, 128, stream);

    router_kernel<<<dim3(TOKENS / 4), 256, 0, stream>>>(
        x, rw, rb, out_rw, out_dm, out_logits,
        counts, probsum, gatesum, lists, glists);
    finalize_kernel<<<1, 64, 0, stream>>>(counts, probsum, gatesum, offs, out_aux);

    if (ws_size >= need) {
        convx_kernel<<<dim3((TOKENS * HID / 4) / 256), 256, 0, stream>>>(x, Xb);
        convT_kernel<<<dim3(FFN_DIM / 32, HID / 64, NEXP), 256, 0, stream>>>(w1, W1T, HID, FFN_DIM);
        convT_kernel<<<dim3(HID / 32, FFN_DIM / 64, NEXP), 256, 0, stream>>>(w2, W2T, FFN_DIM, HID);
        gemm1_kernel<<<dim3(FFN_DIM / 128, TOKENS / 128, NEXP), 256, 0, stream>>>(
            Xb, W1T, b1, counts, offs, lists, Hbuf);
        gemm2_kernel<<<dim3(HID / 128, TOKENS / 128, NEXP), 256, 0, stream>>>(
            Hbuf, W2T, b2, counts, offs, lists, glists, out_comb);
    } else {
        ffn_kernel<<<dim3(TOKENS / BM, NEXP), 256, 0, stream>>>(
            x, w1, b1, w2, b2, counts, lists, glists, out_comb);
    }
}

// Round 3
// 1390.143 us; speedup vs baseline: 14.0150x; 13.9805x over previous
//
#include <hip/hip_runtime.h>
#include <math.h>

#define TOKENS 16384
#define HID 768
#define FFN_DIM 3072
#define NEXP 8
#define MAX_TILES 264   // ceil((2*TOKENS + NEXP*127)/128) rounded: 33792/128

typedef __bf16 bf16x8 __attribute__((ext_vector_type(8)));
typedef float f32x4 __attribute__((ext_vector_type(4)));

#define GLOBAL_AS(p) ((const __attribute__((address_space(1))) void*)(p))
#define LDS_AS(p)    ((__attribute__((address_space(3))) void*)(p))

__device__ __forceinline__ float gelu_f(float x) {
    const float x3 = x * x * x;
    const float z = 0.7978845608028654f * (x + 0.044715f * x3);
    const float e = __expf(2.f * z);
    const float t = 1.f - 2.f / (e + 1.f);   // tanh(z)
    return 0.5f * x * (1.f + t);
}

__device__ __forceinline__ unsigned short f2bf(float v) {
    return __builtin_bit_cast(unsigned short, (__bf16)v);
}

// ---------------- router ----------------
__global__ void __launch_bounds__(256) router_kernel(
    const float* __restrict__ x, const float* __restrict__ rw,
    const float* __restrict__ rb,
    float* __restrict__ out_rw, float* __restrict__ out_dm,
    float* __restrict__ out_logits,
    int* __restrict__ counts, float* __restrict__ probsum,
    float* __restrict__ gatesum, int* __restrict__ lists,
    float* __restrict__ glists)
{
    __shared__ float s_prob[NEXP], s_gate[NEXP];
    if (threadIdx.x < NEXP) { s_prob[threadIdx.x] = 0.f; s_gate[threadIdx.x] = 0.f; }
    __syncthreads();
    const int wave = threadIdx.x >> 6, lane = threadIdx.x & 63;
    const int t = blockIdx.x * 4 + wave;
    const float* xr = x + (size_t)t * HID;
    float acc[NEXP];
#pragma unroll
    for (int e = 0; e < NEXP; ++e) acc[e] = 0.f;
#pragma unroll
    for (int j = 0; j < 12; ++j) {
        const int i = lane + (j << 6);
        const float xv = xr[i];
        const float4 a = ((const float4*)(rw + (size_t)i * NEXP))[0];
        const float4 b = ((const float4*)(rw + (size_t)i * NEXP))[1];
        acc[0] += xv * a.x; acc[1] += xv * a.y; acc[2] += xv * a.z; acc[3] += xv * a.w;
        acc[4] += xv * b.x; acc[5] += xv * b.y; acc[6] += xv * b.z; acc[7] += xv * b.w;
    }
#pragma unroll
    for (int off = 32; off > 0; off >>= 1)
#pragma unroll
        for (int e = 0; e < NEXP; ++e) acc[e] += __shfl_down(acc[e], off, 64);

    if (lane == 0) {
        float lg[NEXP];
        float m = -1e30f;
#pragma unroll
        for (int e = 0; e < NEXP; ++e) { lg[e] = acc[e] + rb[e]; m = fmaxf(m, lg[e]); }
        float ex[NEXP]; float s = 0.f;
#pragma unroll
        for (int e = 0; e < NEXP; ++e) { ex[e] = expf(lg[e] - m); s += ex[e]; }
        const float inv = 1.f / s;
        float* lrow = out_logits + (size_t)t * NEXP;
        float* prow = out_rw + (size_t)t * NEXP;
#pragma unroll
        for (int e = 0; e < NEXP; ++e) {
            lrow[e] = lg[e];
            const float p = ex[e] * inv;
            prow[e] = p;
            atomicAdd(&s_prob[e], p);
        }
        int i1 = 0;
#pragma unroll
        for (int e = 1; e < NEXP; ++e) if (lg[e] > lg[i1]) i1 = e;
        int i2 = (i1 == 0) ? 1 : 0;
#pragma unroll
        for (int e = 0; e < NEXP; ++e) if (e != i1 && lg[e] > lg[i2]) i2 = e;
        const float e2 = expf(lg[i2] - lg[i1]);
        const float g1 = 1.f / (1.f + e2);
        const float g2 = e2 / (1.f + e2);
        out_dm[(size_t)t * NEXP + i1] = g1;
        out_dm[(size_t)t * NEXP + i2] = g2;
        atomicAdd(&s_gate[i1], g1);
        atomicAdd(&s_gate[i2], g2);
        const int s1 = atomicAdd(&counts[i1], 1);
        lists[i1 * TOKENS + s1] = t; glists[i1 * TOKENS + s1] = g1;
        const int s2 = atomicAdd(&counts[i2], 1);
        lists[i2 * TOKENS + s2] = t; glists[i2 * TOKENS + s2] = g2;
    }
    __syncthreads();
    if (threadIdx.x < NEXP) {
        atomicAdd(&probsum[threadIdx.x], s_prob[threadIdx.x]);
        atomicAdd(&gatesum[threadIdx.x], s_gate[threadIdx.x]);
    }
}

// ---------------- finalize: aux loss + padded segment offsets ----------------
__global__ void finalize_kernel(const int* __restrict__ counts,
                                const float* __restrict__ probsum,
                                const float* __restrict__ gatesum,
                                int* __restrict__ poffs,
                                float* __restrict__ out_aux)
{
    if (threadIdx.x == 0 && blockIdx.x == 0) {
        float s = 0.f; int po = 0;
        for (int e = 0; e < NEXP; ++e) {
            poffs[e] = po;
            po += ((counts[e] + 127) >> 7) << 7;   // pad each segment to 128
            s += (probsum[e] / (float)TOKENS) * (gatesum[e] / (float)TOKENS);
        }
        poffs[NEXP] = po;
        *out_aux = s * (float)NEXP;
    }
}

// ---------------- conversions ----------------
__global__ void __launch_bounds__(256) convx_kernel(const float* __restrict__ x,
                                                    unsigned short* __restrict__ xb)
{
    const int i = blockIdx.x * 256 + threadIdx.x;
    const float4 v = ((const float4*)x)[i];
    uint2 o;
    o.x = (unsigned)f2bf(v.x) | ((unsigned)f2bf(v.y) << 16);
    o.y = (unsigned)f2bf(v.z) | ((unsigned)f2bf(v.w) << 16);
    ((uint2*)xb)[i] = o;
}

// fp32 [E][R][C] -> bf16 transposed [E][C][R]
__global__ void __launch_bounds__(256) convT_kernel(const float* __restrict__ in,
                                                    unsigned short* __restrict__ out,
                                                    int R, int C)
{
    __shared__ float sT[32][65];
    const int e = blockIdx.z;
    const float* in_e = in + (size_t)e * R * C;
    unsigned short* out_e = out + (size_t)e * R * C;
    const int r0 = blockIdx.y * 64;
    const int c0 = blockIdx.x * 32;
    const int tid = threadIdx.x;
    const int rr = tid >> 3, c4 = (tid & 7) * 4;
#pragma unroll
    for (int half = 0; half < 2; ++half) {
        const int r = rr + half * 32;
        const float4 v = *(const float4*)&in_e[(size_t)(r0 + r) * C + c0 + c4];
        sT[c4 + 0][r] = v.x; sT[c4 + 1][r] = v.y;
        sT[c4 + 2][r] = v.z; sT[c4 + 3][r] = v.w;
    }
    __syncthreads();
    const int c = tid >> 3, u = tid & 7;
    uint4 pk;
    const float* sr = &sT[c][u * 8];
    pk.x = (unsigned)f2bf(sr[0]) | ((unsigned)f2bf(sr[1]) << 16);
    pk.y = (unsigned)f2bf(sr[2]) | ((unsigned)f2bf(sr[3]) << 16);
    pk.z = (unsigned)f2bf(sr[4]) | ((unsigned)f2bf(sr[5]) << 16);
    pk.w = (unsigned)f2bf(sr[6]) | ((unsigned)f2bf(sr[7]) << 16);
    *(uint4*)&out_e[(size_t)(c0 + c) * R + r0 + u * 8] = pk;
}

// ---------------- GEMM1: H = gelu(Xg @ W1 + b1), bf16 out ----------------
__global__ void __launch_bounds__(256) gemm1_kernel(
    const unsigned short* __restrict__ Xb, const unsigned short* __restrict__ W1T,
    const float* __restrict__ b1, const int* __restrict__ counts,
    const int* __restrict__ poffs, const int* __restrict__ lists,
    unsigned short* __restrict__ H, int grBase)
{
    const int gr = grBase + blockIdx.y * 128;       // global padded row
    if (gr >= poffs[NEXP]) return;
    int e = 0;
#pragma unroll
    for (int q = 1; q < NEXP; ++q) e += (gr >= poffs[q]);
    const int cnt = counts[e];
    const int m0 = gr - poffs[e];                   // expert-local row base
    const int hbase = gr - grBase;                  // group-local H row base
    const int n0 = blockIdx.x * 128;

    __shared__ __bf16 sA[128 * 64];
    __shared__ __bf16 sB[128 * 64];
    __shared__ int sTok[128];

    const int tid = threadIdx.x;
    const int w = tid >> 6, lane = tid & 63;
    if (tid < 128) {
        int ri = m0 + tid; if (ri > cnt - 1) ri = cnt - 1;
        sTok[tid] = lists[e * TOKENS + ri];
    }
    __syncthreads();

    const unsigned short* w1e = W1T + (size_t)e * (FFN_DIM * HID);
    const int lr = lane >> 3;
    const int lk = (lane & 7) * 8;
    const unsigned short* aPtr[4];
    const unsigned short* bPtr[4];
    __bf16* ldsA[4];
    __bf16* ldsB[4];
#pragma unroll
    for (int j = 0; j < 4; ++j) {
        const int row = (w * 4 + j) * 8 + lr;
        aPtr[j] = Xb + (size_t)sTok[row] * HID + lk;
        bPtr[j] = w1e + (size_t)(n0 + row) * HID + lk;
        ldsA[j] = sA + (w * 4 + j) * 512;
        ldsB[j] = sB + (w * 4 + j) * 512;
    }

    f32x4 acc[4][4];
#pragma unroll
    for (int a = 0; a < 4; ++a)
#pragma unroll
        for (int b = 0; b < 4; ++b) acc[a][b] = (f32x4)(0.f);

    const int wm = (w >> 1) * 64, wn = (w & 1) * 64;
    const int fr = lane & 15;
    const int fk = (lane >> 4) * 8;

    for (int kt = 0; kt < HID / 64; ++kt) {
        const int k0 = kt * 64;
#pragma unroll
        for (int j = 0; j < 4; ++j) {
            __builtin_amdgcn_global_load_lds(GLOBAL_AS(aPtr[j] + k0), LDS_AS(ldsA[j]), 16, 0, 0);
            __builtin_amdgcn_global_load_lds(GLOBAL_AS(bPtr[j] + k0), LDS_AS(ldsB[j]), 16, 0, 0);
        }
        __syncthreads();
#pragma unroll
        for (int kk = 0; kk < 64; kk += 32) {
            bf16x8 af[4], bb[4];
#pragma unroll
            for (int t = 0; t < 4; ++t) {
                af[t] = *(const bf16x8*)&sA[(wm + t * 16 + fr) * 64 + kk + fk];
                bb[t] = *(const bf16x8*)&sB[(wn + t * 16 + fr) * 64 + kk + fk];
            }
#pragma unroll
            for (int tm = 0; tm < 4; ++tm)
#pragma unroll
                for (int tn = 0; tn < 4; ++tn)
                    acc[tm][tn] = __builtin_amdgcn_mfma_f32_16x16x32_bf16(
                        af[tm], bb[tn], acc[tm][tn], 0, 0, 0);
        }
        __syncthreads();
    }

    const float* b1e = b1 + (size_t)e * FFN_DIM;
    float bias[4];
#pragma unroll
    for (int tn = 0; tn < 4; ++tn) bias[tn] = b1e[n0 + wn + tn * 16 + fr];
#pragma unroll
    for (int tm = 0; tm < 4; ++tm) {
#pragma unroll
        for (int tn = 0; tn < 4; ++tn) {
            const int n = n0 + wn + tn * 16 + fr;
#pragma unroll
            for (int r = 0; r < 4; ++r) {
                const int mloc = wm + tm * 16 + (lane >> 4) * 4 + r;
                if (m0 + mloc < cnt) {
                    const float h = gelu_f(acc[tm][tn][r] + bias[tn]);
                    H[(size_t)(hbase + mloc) * FFN_DIM + n] = f2bf(h);
                }
            }
        }
    }
}

// ---------------- GEMM2: out[tok] += gate*(H @ W2 + b2) ----------------
__global__ void __launch_bounds__(256) gemm2_kernel(
    const unsigned short* __restrict__ H, const unsigned short* __restrict__ W2T,
    const float* __restrict__ b2, const int* __restrict__ counts,
    const int* __restrict__ poffs, const int* __restrict__ lists,
    const float* __restrict__ glists, float* __restrict__ out, int grBase)
{
    const int gr = grBase + blockIdx.y * 128;
    if (gr >= poffs[NEXP]) return;
    int e = 0;
#pragma unroll
    for (int q = 1; q < NEXP; ++q) e += (gr >= poffs[q]);
    const int cnt = counts[e];
    const int m0 = gr - poffs[e];
    const int hbase = gr - grBase;
    const int n0 = blockIdx.x * 128;

    __shared__ __bf16 sA[128 * 64];
    __shared__ __bf16 sB[128 * 64];
    __shared__ int sTok[128];
    __shared__ float sGate[128];

    const int tid = threadIdx.x;
    const int w = tid >> 6, lane = tid & 63;
    if (tid < 128) {
        int ri = m0 + tid; if (ri > cnt - 1) ri = cnt - 1;
        sTok[tid] = lists[e * TOKENS + ri];
        sGate[tid] = glists[e * TOKENS + ri];
    }
    __syncthreads();

    const unsigned short* w2e = W2T + (size_t)e * (FFN_DIM * HID);
    const int lr = lane >> 3;
    const int lk = (lane & 7) * 8;
    const unsigned short* aPtr[4];
    const unsigned short* bPtr[4];
    __bf16* ldsA[4];
    __bf16* ldsB[4];
#pragma unroll
    for (int j = 0; j < 4; ++j) {
        const int row = (w * 4 + j) * 8 + lr;
        aPtr[j] = H + (size_t)(hbase + row) * FFN_DIM + lk;
        bPtr[j] = w2e + (size_t)(n0 + row) * FFN_DIM + lk;
        ldsA[j] = sA + (w * 4 + j) * 512;
        ldsB[j] = sB + (w * 4 + j) * 512;
    }

    f32x4 acc[4][4];
#pragma unroll
    for (int a = 0; a < 4; ++a)
#pragma unroll
        for (int b = 0; b < 4; ++b) acc[a][b] = (f32x4)(0.f);

    const int wm = (w >> 1) * 64, wn = (w & 1) * 64;
    const int fr = lane & 15;
    const int fk = (lane >> 4) * 8;

    for (int kt = 0; kt < FFN_DIM / 64; ++kt) {
        const int k0 = kt * 64;
#pragma unroll
        for (int j = 0; j < 4; ++j) {
            __builtin_amdgcn_global_load_lds(GLOBAL_AS(aPtr[j] + k0), LDS_AS(ldsA[j]), 16, 0, 0);
            __builtin_amdgcn_global_load_lds(GLOBAL_AS(bPtr[j] + k0), LDS_AS(ldsB[j]), 16, 0, 0);
        }
        __syncthreads();
#pragma unroll
        for (int kk = 0; kk < 64; kk += 32) {
            bf16x8 af[4], bb[4];
#pragma unroll
            for (int t = 0; t < 4; ++t) {
                af[t] = *(const bf16x8*)&sA[(wm + t * 16 + fr) * 64 + kk + fk];
                bb[t] = *(const bf16x8*)&sB[(wn + t * 16 + fr) * 64 + kk + fk];
            }
#pragma unroll
            for (int tm = 0; tm < 4; ++tm)
#pragma unroll
                for (int tn = 0; tn < 4; ++tn)
                    acc[tm][tn] = __builtin_amdgcn_mfma_f32_16x16x32_bf16(
                        af[tm], bb[tn], acc[tm][tn], 0, 0, 0);
        }
        __syncthreads();
    }

    const float* b2e = b2 + (size_t)e * HID;
    float bias[4];
#pragma unroll
    for (int tn = 0; tn < 4; ++tn) bias[tn] = b2e[n0 + wn + tn * 16 + fr];
#pragma unroll
    for (int tm = 0; tm < 4; ++tm) {
#pragma unroll
        for (int tn = 0; tn < 4; ++tn) {
            const int n = n0 + wn + tn * 16 + fr;
#pragma unroll
            for (int r = 0; r < 4; ++r) {
                const int mloc = wm + tm * 16 + (lane >> 4) * 4 + r;
                if (m0 + mloc < cnt) {
                    const float y = acc[tm][tn][r] + bias[tn];
                    atomicAdd(&out[(size_t)sTok[mloc] * HID + n], sGate[mloc] * y);
                }
            }
        }
    }
}

// ---------------- fallback fp32 FFN ----------------
#define BM 16
#define KC 64
#define XS 772
#define HS 68
__global__ void __launch_bounds__(256) ffn_kernel(
    const float* __restrict__ x, const float* __restrict__ w1,
    const float* __restrict__ b1, const float* __restrict__ w2,
    const float* __restrict__ b2, const int* __restrict__ counts,
    const int* __restrict__ lists, const float* __restrict__ glists,
    float* __restrict__ out)
{
    const int e = blockIdx.y;
    const int count = counts[e];
    const int row0 = blockIdx.x * BM;
    if (row0 >= count) return;

    __shared__ float sX[BM * XS];
    __shared__ float sH[BM * HS];
    __shared__ int sTokF[BM];
    __shared__ float sGateF[BM];
    const int tid = threadIdx.x;

    if (tid < BM) {
        const int ri = row0 + tid;
        int tok = 0; float g = 0.f;
        if (ri < count) { tok = lists[e * TOKENS + ri]; g = glists[e * TOKENS + ri]; }
        sTokF[tid] = tok; sGateF[tid] = g;
    }
    __syncthreads();
    {
        const int r = tid >> 4, q = tid & 15;
        const float4* src = (const float4*)(x + (size_t)sTokF[r] * HID);
#pragma unroll
        for (int j = 0; j < 12; ++j) {
            const float4 v = src[q + (j << 4)];
            *(float4*)&sX[r * XS + ((q + (j << 4)) << 2)] = v;
        }
    }
    __syncthreads();

    const float* w1e = w1 + (size_t)e * HID * FFN_DIM;
    const float* w2e = w2 + (size_t)e * FFN_DIM * HID;
    const float* b1e = b1 + (size_t)e * FFN_DIM;
    const float* b2e = b2 + (size_t)e * HID;
    const int r1 = tid & 15;
    const int c0 = (tid >> 4) << 2;
    const int c2 = (tid >> 4) * 48;

    float Y[48];
#pragma unroll
    for (int j = 0; j < 48; ++j) Y[j] = 0.f;

    for (int ch = 0; ch < FFN_DIM / KC; ++ch) {
        float h0 = 0.f, h1 = 0.f, h2 = 0.f, h3 = 0.f;
        const float* w1c = w1e + ch * KC + c0;
        for (int i = 0; i < HID; i += 4) {
            const float4 xv = *(const float4*)&sX[r1 * XS + i];
            const float* wp = w1c + (size_t)i * FFN_DIM;
            const float4 wa = *(const float4*)(wp);
            const float4 wb = *(const float4*)(wp + FFN_DIM);
            const float4 wc = *(const float4*)(wp + 2 * FFN_DIM);
            const float4 wd = *(const float4*)(wp + 3 * FFN_DIM);
            h0 += xv.x * wa.x + xv.y * wb.x + xv.z * wc.x + xv.w * wd.x;
            h1 += xv.x * wa.y + xv.y * wb.y + xv.z * wc.y + xv.w * wd.y;
            h2 += xv.x * wa.z + xv.y * wb.z + xv.z * wc.z + xv.w * wd.z;
            h3 += xv.x * wa.w + xv.y * wb.w + xv.z * wc.w + xv.w * wd.w;
        }
        const int cb = ch * KC + c0;
        h0 = gelu_f(h0 + b1e[cb + 0]);
        h1 = gelu_f(h1 + b1e[cb + 1]);
        h2 = gelu_f(h2 + b1e[cb + 2]);
        h3 = gelu_f(h3 + b1e[cb + 3]);
        __syncthreads();
        *(float4*)&sH[r1 * HS + c0] = make_float4(h0, h1, h2, h3);
        __syncthreads();
        const float* w2c = w2e + (size_t)ch * KC * HID + c2;
        for (int k = 0; k < KC; ++k) {
            const float hv = sH[r1 * HS + k];
            const float4* wr = (const float4*)(w2c + (size_t)k * HID);
#pragma unroll
            for (int j4 = 0; j4 < 12; ++j4) {
                const float4 wv = wr[j4];
                Y[j4 * 4 + 0] += hv * wv.x;
                Y[j4 * 4 + 1] += hv * wv.y;
                Y[j4 * 4 + 2] += hv * wv.z;
                Y[j4 * 4 + 3] += hv * wv.w;
            }
        }
    }
    const int ri = row0 + r1;
    if (ri < count) {
        const float g = sGateF[r1];
        float* orow = out + (size_t)sTokF[r1] * HID + c2;
#pragma unroll
        for (int j = 0; j < 48; ++j)
            atomicAdd(&orow[j], g * (Y[j] + b2e[c2 + j]));
    }
}

extern "C" void kernel_launch(void* const* d_in, const int* in_sizes, int n_in,
                              void* d_out, int out_size, void* d_ws, size_t ws_size,
                              hipStream_t stream)
{
    const float* x  = (const float*)d_in[0];
    const float* rw = (const float*)d_in[1];
    const float* rb = (const float*)d_in[2];
    const float* w1 = (const float*)d_in[3];
    const float* b1 = (const float*)d_in[4];
    const float* w2 = (const float*)d_in[5];
    const float* b2 = (const float*)d_in[6];

    float* out = (float*)d_out;
    float* out_comb   = out;
    float* out_rw     = out + (size_t)TOKENS * HID;
    float* out_dm     = out_rw + (size_t)TOKENS * NEXP;
    float* out_aux    = out_dm + (size_t)TOKENS * NEXP;
    float* out_logits = out_aux + 1;

    char* ws = (char*)d_ws;
    int*   counts  = (int*)ws;              // 32 B
    int*   poffs   = (int*)(ws + 64);       // 9 ints
    float* probsum = (float*)(ws + 128);
    float* gatesum = (float*)(ws + 160);
    int*   lists   = (int*)(ws + 256);
    float* glists  = (float*)(ws + 256 + (size_t)NEXP * TOKENS * 4);
    size_t off = 256 + (size_t)NEXP * TOKENS * 8;
    off = (off + 255) & ~(size_t)255;
    unsigned short* Xb  = (unsigned short*)(ws + off); off += (size_t)TOKENS * HID * 2;
    unsigned short* W1T = (unsigned short*)(ws + off); off += (size_t)NEXP * HID * FFN_DIM * 2;
    unsigned short* W2T = (unsigned short*)(ws + off); off += (size_t)NEXP * HID * FFN_DIM * 2;
    unsigned short* Hbuf = (unsigned short*)(ws + off);
    const size_t fixed = off;

    // pick smallest group count G whose Hbuf fits the remaining workspace
    int G = -1, tilesPG = 0;
    const int cand[6] = {1, 2, 4, 8, 16, 32};
    for (int ci = 0; ci < 6; ++ci) {
        const int g = cand[ci];
        const int t = (MAX_TILES + g - 1) / g;
        const size_t need = fixed + (size_t)t * 128 * FFN_DIM * 2;
        if (need <= ws_size) { G = g; tilesPG = t; break; }
    }

    hipMemsetAsync(out_comb, 0, (size_t)TOKENS * HID * sizeof(float), stream);
    hipMemsetAsync(out_dm, 0, (size_t)TOKENS * NEXP * sizeof(float), stream);
    hipMemsetAsync(d_ws, 0, 256, stream);

    router_kernel<<<dim3(TOKENS / 4), 256, 0, stream>>>(
        x, rw, rb, out_rw, out_dm, out_logits,
        counts, probsum, gatesum, lists, glists);
    finalize_kernel<<<1, 64, 0, stream>>>(counts, probsum, gatesum, poffs, out_aux);

    if (G > 0) {
        convx_kernel<<<dim3((TOKENS * HID / 4) / 256), 256, 0, stream>>>(x, Xb);
        convT_kernel<<<dim3(FFN_DIM / 32, HID / 64, NEXP), 256, 0, stream>>>(w1, W1T, HID, FFN_DIM);
        convT_kernel<<<dim3(HID / 32, FFN_DIM / 64, NEXP), 256, 0, stream>>>(w2, W2T, FFN_DIM, HID);
        for (int g = 0; g < G; ++g) {
            const int grBase = g * tilesPG * 128;
            gemm1_kernel<<<dim3(FFN_DIM / 128, tilesPG), 256, 0, stream>>>(
                Xb, W1T, b1, counts, poffs, lists, Hbuf, grBase);
            gemm2_kernel<<<dim3(HID / 128, tilesPG), 256, 0, stream>>>(
                Hbuf, W2T, b2, counts, poffs, lists, glists, out_comb, grBase);
        }
    } else {
        ffn_kernel<<<dim3(TOKENS / BM, NEXP), 256, 0, stream>>>(
            x, w1, b1, w2, b2, counts, lists, glists, out_comb);
    }
}

// Round 4
// 1054.862 us; speedup vs baseline: 18.4696x; 1.3178x over previous
//
#include <hip/hip_runtime.h>
#include <math.h>

#define TOKENS 16384
#define HID 768
#define FFN_DIM 3072
#define NEXP 8
#define MAX_TILES 264   // ceil padded rows / 128 upper bound

#define RT_TPB 128      // router tokens per block
#define RT_BLOCKS (TOKENS / RT_TPB)

typedef __bf16 bf16x8 __attribute__((ext_vector_type(8)));
typedef float f32x4 __attribute__((ext_vector_type(4)));

#define GLOBAL_AS(p) ((const __attribute__((address_space(1))) void*)(p))
#define LDS_AS(p)    ((__attribute__((address_space(3))) void*)(p))

__device__ __forceinline__ float gelu_f(float x) {
    const float x3 = x * x * x;
    const float z = 0.7978845608028654f * (x + 0.044715f * x3);
    const float e = __expf(2.f * z);
    const float t = 1.f - 2.f / (e + 1.f);   // tanh(z)
    return 0.5f * x * (1.f + t);
}

__device__ __forceinline__ unsigned short f2bf(float v) {
    return __builtin_bit_cast(unsigned short, (__bf16)v);
}

// ---------------- router (block-aggregated atomics) ----------------
__global__ void __launch_bounds__(512) router_kernel(
    const float* __restrict__ x, const float* __restrict__ rw,
    const float* __restrict__ rb,
    float* __restrict__ out_rw, float* __restrict__ out_dm,
    float* __restrict__ out_logits,
    int* __restrict__ counts, float* __restrict__ probsum,
    float* __restrict__ gatesum, int* __restrict__ lists,
    float* __restrict__ glists)
{
    __shared__ int s_cnt[NEXP], s_base[NEXP];
    __shared__ float s_prob[NEXP], s_gate[NEXP];
    __shared__ int s_e1[RT_TPB], s_s1[RT_TPB], s_e2[RT_TPB], s_s2[RT_TPB];
    __shared__ float s_g1v[RT_TPB], s_g2v[RT_TPB];

    const int tid = threadIdx.x;
    if (tid < NEXP) { s_cnt[tid] = 0; s_prob[tid] = 0.f; s_gate[tid] = 0.f; }
    __syncthreads();

    const int wave = tid >> 6, lane = tid & 63;

    for (int it = 0; it < RT_TPB / 8; ++it) {   // 16 tokens per wave
        const int lt = wave * (RT_TPB / 8) + it;
        const int t = blockIdx.x * RT_TPB + lt;
        const float* xr = x + (size_t)t * HID;
        float acc[NEXP];
#pragma unroll
        for (int e = 0; e < NEXP; ++e) acc[e] = 0.f;
#pragma unroll
        for (int j = 0; j < 12; ++j) {
            const int i = lane + (j << 6);
            const float xv = xr[i];
            const float4 a = ((const float4*)(rw + (size_t)i * NEXP))[0];
            const float4 b = ((const float4*)(rw + (size_t)i * NEXP))[1];
            acc[0] += xv * a.x; acc[1] += xv * a.y; acc[2] += xv * a.z; acc[3] += xv * a.w;
            acc[4] += xv * b.x; acc[5] += xv * b.y; acc[6] += xv * b.z; acc[7] += xv * b.w;
        }
#pragma unroll
        for (int off = 32; off > 0; off >>= 1)
#pragma unroll
            for (int e = 0; e < NEXP; ++e) acc[e] += __shfl_down(acc[e], off, 64);

        if (lane == 0) {
            float lg[NEXP];
            float m = -1e30f;
#pragma unroll
            for (int e = 0; e < NEXP; ++e) { lg[e] = acc[e] + rb[e]; m = fmaxf(m, lg[e]); }
            float ex[NEXP]; float s = 0.f;
#pragma unroll
            for (int e = 0; e < NEXP; ++e) { ex[e] = expf(lg[e] - m); s += ex[e]; }
            const float inv = 1.f / s;
            float* lrow = out_logits + (size_t)t * NEXP;
            float* prow = out_rw + (size_t)t * NEXP;
#pragma unroll
            for (int e = 0; e < NEXP; ++e) {
                lrow[e] = lg[e];
                const float p = ex[e] * inv;
                prow[e] = p;
                atomicAdd(&s_prob[e], p);
            }
            int i1 = 0;
#pragma unroll
            for (int e = 1; e < NEXP; ++e) if (lg[e] > lg[i1]) i1 = e;
            int i2 = (i1 == 0) ? 1 : 0;
#pragma unroll
            for (int e = 0; e < NEXP; ++e) if (e != i1 && lg[e] > lg[i2]) i2 = e;
            const float e2 = expf(lg[i2] - lg[i1]);
            const float g1 = 1.f / (1.f + e2);
            const float g2 = e2 / (1.f + e2);
            out_dm[(size_t)t * NEXP + i1] = g1;
            out_dm[(size_t)t * NEXP + i2] = g2;
            atomicAdd(&s_gate[i1], g1);
            atomicAdd(&s_gate[i2], g2);
            s_e1[lt] = i1; s_s1[lt] = atomicAdd(&s_cnt[i1], 1); s_g1v[lt] = g1;
            s_e2[lt] = i2; s_s2[lt] = atomicAdd(&s_cnt[i2], 1); s_g2v[lt] = g2;
        }
    }
    __syncthreads();
    if (tid < NEXP) {
        s_base[tid] = atomicAdd(&counts[tid], s_cnt[tid]);   // 1 contended RMW per block per expert
        atomicAdd(&probsum[tid], s_prob[tid]);
        atomicAdd(&gatesum[tid], s_gate[tid]);
    }
    __syncthreads();
    if (tid < RT_TPB) {
        const int t = blockIdx.x * RT_TPB + tid;
        int e = s_e1[tid]; int p = s_base[e] + s_s1[tid];
        lists[e * TOKENS + p] = t; glists[e * TOKENS + p] = s_g1v[tid];
        e = s_e2[tid]; p = s_base[e] + s_s2[tid];
        lists[e * TOKENS + p] = t; glists[e * TOKENS + p] = s_g2v[tid];
    }
}

// ---------------- finalize: aux loss + padded segment offsets ----------------
__global__ void finalize_kernel(const int* __restrict__ counts,
                                const float* __restrict__ probsum,
                                const float* __restrict__ gatesum,
                                int* __restrict__ poffs,
                                float* __restrict__ out_aux)
{
    if (threadIdx.x == 0 && blockIdx.x == 0) {
        float s = 0.f; int po = 0;
        for (int e = 0; e < NEXP; ++e) {
            poffs[e] = po;
            po += ((counts[e] + 127) >> 7) << 7;   // pad each segment to 128
            s += (probsum[e] / (float)TOKENS) * (gatesum[e] / (float)TOKENS);
        }
        poffs[NEXP] = po;
        *out_aux = s * (float)NEXP;
    }
}

// ---------------- conversions ----------------
__global__ void __launch_bounds__(256) convx_kernel(const float* __restrict__ x,
                                                    unsigned short* __restrict__ xb)
{
    const int i = blockIdx.x * 256 + threadIdx.x;
    const float4 v = ((const float4*)x)[i];
    uint2 o;
    o.x = (unsigned)f2bf(v.x) | ((unsigned)f2bf(v.y) << 16);
    o.y = (unsigned)f2bf(v.z) | ((unsigned)f2bf(v.w) << 16);
    ((uint2*)xb)[i] = o;
}

// fp32 [E][R][C] -> bf16 transposed [E][C][R]
__global__ void __launch_bounds__(256) convT_kernel(const float* __restrict__ in,
                                                    unsigned short* __restrict__ out,
                                                    int R, int C)
{
    __shared__ float sT[32][65];
    const int e = blockIdx.z;
    const float* in_e = in + (size_t)e * R * C;
    unsigned short* out_e = out + (size_t)e * R * C;
    const int r0 = blockIdx.y * 64;
    const int c0 = blockIdx.x * 32;
    const int tid = threadIdx.x;
    const int rr = tid >> 3, c4 = (tid & 7) * 4;
#pragma unroll
    for (int half = 0; half < 2; ++half) {
        const int r = rr + half * 32;
        const float4 v = *(const float4*)&in_e[(size_t)(r0 + r) * C + c0 + c4];
        sT[c4 + 0][r] = v.x; sT[c4 + 1][r] = v.y;
        sT[c4 + 2][r] = v.z; sT[c4 + 3][r] = v.w;
    }
    __syncthreads();
    const int c = tid >> 3, u = tid & 7;
    uint4 pk;
    const float* sr = &sT[c][u * 8];
    pk.x = (unsigned)f2bf(sr[0]) | ((unsigned)f2bf(sr[1]) << 16);
    pk.y = (unsigned)f2bf(sr[2]) | ((unsigned)f2bf(sr[3]) << 16);
    pk.z = (unsigned)f2bf(sr[4]) | ((unsigned)f2bf(sr[5]) << 16);
    pk.w = (unsigned)f2bf(sr[6]) | ((unsigned)f2bf(sr[7]) << 16);
    *(uint4*)&out_e[(size_t)(c0 + c) * R + r0 + u * 8] = pk;
}

// ---------------- GEMM1: H = gelu(Xg @ W1 + b1), bf16 out ----------------
__global__ void __launch_bounds__(256) gemm1_kernel(
    const unsigned short* __restrict__ Xb, const unsigned short* __restrict__ W1T,
    const float* __restrict__ b1, const int* __restrict__ counts,
    const int* __restrict__ poffs, const int* __restrict__ lists,
    unsigned short* __restrict__ H, int grBase)
{
    const int gr = grBase + blockIdx.y * 128;       // global padded row
    if (gr >= poffs[NEXP]) return;
    int e = 0;
#pragma unroll
    for (int q = 1; q < NEXP; ++q) e += (gr >= poffs[q]);
    const int cnt = counts[e];
    const int m0 = gr - poffs[e];
    const int hbase = gr - grBase;
    const int n0 = blockIdx.x * 128;

    __shared__ __bf16 sA[128 * 64];
    __shared__ __bf16 sB[128 * 64];
    __shared__ int sTok[128];

    const int tid = threadIdx.x;
    const int w = tid >> 6, lane = tid & 63;
    if (tid < 128) {
        int ri = m0 + tid; if (ri > cnt - 1) ri = cnt - 1;
        sTok[tid] = lists[e * TOKENS + ri];
    }
    __syncthreads();

    const unsigned short* w1e = W1T + (size_t)e * (FFN_DIM * HID);
    const int lr = lane >> 3;
    const int lk = (lane & 7) * 8;
    const unsigned short* aPtr[4];
    const unsigned short* bPtr[4];
    __bf16* ldsA[4];
    __bf16* ldsB[4];
#pragma unroll
    for (int j = 0; j < 4; ++j) {
        const int row = (w * 4 + j) * 8 + lr;
        aPtr[j] = Xb + (size_t)sTok[row] * HID + lk;
        bPtr[j] = w1e + (size_t)(n0 + row) * HID + lk;
        ldsA[j] = sA + (w * 4 + j) * 512;
        ldsB[j] = sB + (w * 4 + j) * 512;
    }

    f32x4 acc[4][4];
#pragma unroll
    for (int a = 0; a < 4; ++a)
#pragma unroll
        for (int b = 0; b < 4; ++b) acc[a][b] = (f32x4)(0.f);

    const int wm = (w >> 1) * 64, wn = (w & 1) * 64;
    const int fr = lane & 15;
    const int fk = (lane >> 4) * 8;

    for (int kt = 0; kt < HID / 64; ++kt) {
        const int k0 = kt * 64;
#pragma unroll
        for (int j = 0; j < 4; ++j) {
            __builtin_amdgcn_global_load_lds(GLOBAL_AS(aPtr[j] + k0), LDS_AS(ldsA[j]), 16, 0, 0);
            __builtin_amdgcn_global_load_lds(GLOBAL_AS(bPtr[j] + k0), LDS_AS(ldsB[j]), 16, 0, 0);
        }
        __syncthreads();
#pragma unroll
        for (int kk = 0; kk < 64; kk += 32) {
            bf16x8 af[4], bb[4];
#pragma unroll
            for (int t = 0; t < 4; ++t) {
                af[t] = *(const bf16x8*)&sA[(wm + t * 16 + fr) * 64 + kk + fk];
                bb[t] = *(const bf16x8*)&sB[(wn + t * 16 + fr) * 64 + kk + fk];
            }
#pragma unroll
            for (int tm = 0; tm < 4; ++tm)
#pragma unroll
                for (int tn = 0; tn < 4; ++tn)
                    acc[tm][tn] = __builtin_amdgcn_mfma_f32_16x16x32_bf16(
                        af[tm], bb[tn], acc[tm][tn], 0, 0, 0);
        }
        __syncthreads();
    }

    const float* b1e = b1 + (size_t)e * FFN_DIM;
    float bias[4];
#pragma unroll
    for (int tn = 0; tn < 4; ++tn) bias[tn] = b1e[n0 + wn + tn * 16 + fr];
#pragma unroll
    for (int tm = 0; tm < 4; ++tm) {
#pragma unroll
        for (int tn = 0; tn < 4; ++tn) {
            const int n = n0 + wn + tn * 16 + fr;
#pragma unroll
            for (int r = 0; r < 4; ++r) {
                const int mloc = wm + tm * 16 + (lane >> 4) * 4 + r;
                if (m0 + mloc < cnt) {
                    const float h = gelu_f(acc[tm][tn][r] + bias[tn]);
                    H[(size_t)(hbase + mloc) * FFN_DIM + n] = f2bf(h);
                }
            }
        }
    }
}

// ---------------- GEMM2: out[tok] += gate*(H @ W2 + b2) ----------------
__global__ void __launch_bounds__(256) gemm2_kernel(
    const unsigned short* __restrict__ H, const unsigned short* __restrict__ W2T,
    const float* __restrict__ b2, const int* __restrict__ counts,
    const int* __restrict__ poffs, const int* __restrict__ lists,
    const float* __restrict__ glists, float* __restrict__ out, int grBase)
{
    const int gr = grBase + blockIdx.y * 128;
    if (gr >= poffs[NEXP]) return;
    int e = 0;
#pragma unroll
    for (int q = 1; q < NEXP; ++q) e += (gr >= poffs[q]);
    const int cnt = counts[e];
    const int m0 = gr - poffs[e];
    const int hbase = gr - grBase;
    const int n0 = blockIdx.x * 128;

    __shared__ __bf16 sA[128 * 64];
    __shared__ __bf16 sB[128 * 64];
    __shared__ int sTok[128];
    __shared__ float sGate[128];

    const int tid = threadIdx.x;
    const int w = tid >> 6, lane = tid & 63;
    if (tid < 128) {
        int ri = m0 + tid; if (ri > cnt - 1) ri = cnt - 1;
        sTok[tid] = lists[e * TOKENS + ri];
        sGate[tid] = glists[e * TOKENS + ri];
    }
    __syncthreads();

    const unsigned short* w2e = W2T + (size_t)e * (FFN_DIM * HID);
    const int lr = lane >> 3;
    const int lk = (lane & 7) * 8;
    const unsigned short* aPtr[4];
    const unsigned short* bPtr[4];
    __bf16* ldsA[4];
    __bf16* ldsB[4];
#pragma unroll
    for (int j = 0; j < 4; ++j) {
        const int row = (w * 4 + j) * 8 + lr;
        aPtr[j] = H + (size_t)(hbase + row) * FFN_DIM + lk;
        bPtr[j] = w2e + (size_t)(n0 + row) * FFN_DIM + lk;
        ldsA[j] = sA + (w * 4 + j) * 512;
        ldsB[j] = sB + (w * 4 + j) * 512;
    }

    f32x4 acc[4][4];
#pragma unroll
    for (int a = 0; a < 4; ++a)
#pragma unroll
        for (int b = 0; b < 4; ++b) acc[a][b] = (f32x4)(0.f);

    const int wm = (w >> 1) * 64, wn = (w & 1) * 64;
    const int fr = lane & 15;
    const int fk = (lane >> 4) * 8;

    for (int kt = 0; kt < FFN_DIM / 64; ++kt) {
        const int k0 = kt * 64;
#pragma unroll
        for (int j = 0; j < 4; ++j) {
            __builtin_amdgcn_global_load_lds(GLOBAL_AS(aPtr[j] + k0), LDS_AS(ldsA[j]), 16, 0, 0);
            __builtin_amdgcn_global_load_lds(GLOBAL_AS(bPtr[j] + k0), LDS_AS(ldsB[j]), 16, 0, 0);
        }
        __syncthreads();
#pragma unroll
        for (int kk = 0; kk < 64; kk += 32) {
            bf16x8 af[4], bb[4];
#pragma unroll
            for (int t = 0; t < 4; ++t) {
                af[t] = *(const bf16x8*)&sA[(wm + t * 16 + fr) * 64 + kk + fk];
                bb[t] = *(const bf16x8*)&sB[(wn + t * 16 + fr) * 64 + kk + fk];
            }
#pragma unroll
            for (int tm = 0; tm < 4; ++tm)
#pragma unroll
                for (int tn = 0; tn < 4; ++tn)
                    acc[tm][tn] = __builtin_amdgcn_mfma_f32_16x16x32_bf16(
                        af[tm], bb[tn], acc[tm][tn], 0, 0, 0);
        }
        __syncthreads();
    }

    const float* b2e = b2 + (size_t)e * HID;
    float bias[4];
#pragma unroll
    for (int tn = 0; tn < 4; ++tn) bias[tn] = b2e[n0 + wn + tn * 16 + fr];
#pragma unroll
    for (int tm = 0; tm < 4; ++tm) {
#pragma unroll
        for (int tn = 0; tn < 4; ++tn) {
            const int n = n0 + wn + tn * 16 + fr;
#pragma unroll
            for (int r = 0; r < 4; ++r) {
                const int mloc = wm + tm * 16 + (lane >> 4) * 4 + r;
                if (m0 + mloc < cnt) {
                    const float y = acc[tm][tn][r] + bias[tn];
                    atomicAdd(&out[(size_t)sTok[mloc] * HID + n], sGate[mloc] * y);
                }
            }
        }
    }
}

// ---------------- fallback fp32 FFN ----------------
#define BM 16
#define KC 64
#define XS 772
#define HS 68
__global__ void __launch_bounds__(256) ffn_kernel(
    const float* __restrict__ x, const float* __restrict__ w1,
    const float* __restrict__ b1, const float* __restrict__ w2,
    const float* __restrict__ b2, const int* __restrict__ counts,
    const int* __restrict__ lists, const float* __restrict__ glists,
    float* __restrict__ out)
{
    const int e = blockIdx.y;
    const int count = counts[e];
    const int row0 = blockIdx.x * BM;
    if (row0 >= count) return;

    __shared__ float sX[BM * XS];
    __shared__ float sH[BM * HS];
    __shared__ int sTokF[BM];
    __shared__ float sGateF[BM];
    const int tid = threadIdx.x;

    if (tid < BM) {
        const int ri = row0 + tid;
        int tok = 0; float g = 0.f;
        if (ri < count) { tok = lists[e * TOKENS + ri]; g = glists[e * TOKENS + ri]; }
        sTokF[tid] = tok; sGateF[tid] = g;
    }
    __syncthreads();
    {
        const int r = tid >> 4, q = tid & 15;
        const float4* src = (const float4*)(x + (size_t)sTokF[r] * HID);
#pragma unroll
        for (int j = 0; j < 12; ++j) {
            const float4 v = src[q + (j << 4)];
            *(float4*)&sX[r * XS + ((q + (j << 4)) << 2)] = v;
        }
    }
    __syncthreads();

    const float* w1e = w1 + (size_t)e * HID * FFN_DIM;
    const float* w2e = w2 + (size_t)e * FFN_DIM * HID;
    const float* b1e = b1 + (size_t)e * FFN_DIM;
    const float* b2e = b2 + (size_t)e * HID;
    const int r1 = tid & 15;
    const int c0 = (tid >> 4) << 2;
    const int c2 = (tid >> 4) * 48;

    float Y[48];
#pragma unroll
    for (int j = 0; j < 48; ++j) Y[j] = 0.f;

    for (int ch = 0; ch < FFN_DIM / KC; ++ch) {
        float h0 = 0.f, h1 = 0.f, h2 = 0.f, h3 = 0.f;
        const float* w1c = w1e + ch * KC + c0;
        for (int i = 0; i < HID; i += 4) {
            const float4 xv = *(const float4*)&sX[r1 * XS + i];
            const float* wp = w1c + (size_t)i * FFN_DIM;
            const float4 wa = *(const float4*)(wp);
            const float4 wb = *(const float4*)(wp + FFN_DIM);
            const float4 wc = *(const float4*)(wp + 2 * FFN_DIM);
            const float4 wd = *(const float4*)(wp + 3 * FFN_DIM);
            h0 += xv.x * wa.x + xv.y * wb.x + xv.z * wc.x + xv.w * wd.x;
            h1 += xv.x * wa.y + xv.y * wb.y + xv.z * wc.y + xv.w * wd.y;
            h2 += xv.x * wa.z + xv.y * wb.z + xv.z * wc.z + xv.w * wd.z;
            h3 += xv.x * wa.w + xv.y * wb.w + xv.z * wc.w + xv.w * wd.w;
        }
        const int cb = ch * KC + c0;
        h0 = gelu_f(h0 + b1e[cb + 0]);
        h1 = gelu_f(h1 + b1e[cb + 1]);
        h2 = gelu_f(h2 + b1e[cb + 2]);
        h3 = gelu_f(h3 + b1e[cb + 3]);
        __syncthreads();
        *(float4*)&sH[r1 * HS + c0] = make_float4(h0, h1, h2, h3);
        __syncthreads();
        const float* w2c = w2e + (size_t)ch * KC * HID + c2;
        for (int k = 0; k < KC; ++k) {
            const float hv = sH[r1 * HS + k];
            const float4* wr = (const float4*)(w2c + (size_t)k * HID);
#pragma unroll
            for (int j4 = 0; j4 < 12; ++j4) {
                const float4 wv = wr[j4];
                Y[j4 * 4 + 0] += hv * wv.x;
                Y[j4 * 4 + 1] += hv * wv.y;
                Y[j4 * 4 + 2] += hv * wv.z;
                Y[j4 * 4 + 3] += hv * wv.w;
            }
        }
    }
    const int ri = row0 + r1;
    if (ri < count) {
        const float g = sGateF[r1];
        float* orow = out + (size_t)sTokF[r1] * HID + c2;
#pragma unroll
        for (int j = 0; j < 48; ++j)
            atomicAdd(&orow[j], g * (Y[j] + b2e[c2 + j]));
    }
}

extern "C" void kernel_launch(void* const* d_in, const int* in_sizes, int n_in,
                              void* d_out, int out_size, void* d_ws, size_t ws_size,
                              hipStream_t stream)
{
    const float* x  = (const float*)d_in[0];
    const float* rw = (const float*)d_in[1];
    const float* rb = (const float*)d_in[2];
    const float* w1 = (const float*)d_in[3];
    const float* b1 = (const float*)d_in[4];
    const float* w2 = (const float*)d_in[5];
    const float* b2 = (const float*)d_in[6];

    float* out = (float*)d_out;
    float* out_comb   = out;
    float* out_rw     = out + (size_t)TOKENS * HID;
    float* out_dm     = out_rw + (size_t)TOKENS * NEXP;
    float* out_aux    = out_dm + (size_t)TOKENS * NEXP;
    float* out_logits = out_aux + 1;

    char* ws = (char*)d_ws;
    int*   counts  = (int*)ws;
    int*   poffs   = (int*)(ws + 64);
    float* probsum = (float*)(ws + 128);
    float* gatesum = (float*)(ws + 160);
    int*   lists   = (int*)(ws + 256);
    float* glists  = (float*)(ws + 256 + (size_t)NEXP * TOKENS * 4);
    size_t off = 256 + (size_t)NEXP * TOKENS * 8;
    off = (off + 255) & ~(size_t)255;
    unsigned short* Xb  = (unsigned short*)(ws + off); off += (size_t)TOKENS * HID * 2;
    unsigned short* W1T = (unsigned short*)(ws + off); off += (size_t)NEXP * HID * FFN_DIM * 2;
    unsigned short* W2T = (unsigned short*)(ws + off); off += (size_t)NEXP * HID * FFN_DIM * 2;
    unsigned short* Hbuf = (unsigned short*)(ws + off);
    const size_t fixed = off;

    int G = -1, tilesPG = 0;
    const int cand[6] = {1, 2, 4, 8, 16, 32};
    for (int ci = 0; ci < 6; ++ci) {
        const int g = cand[ci];
        const int t = (MAX_TILES + g - 1) / g;
        const size_t need = fixed + (size_t)t * 128 * FFN_DIM * 2;
        if (need <= ws_size) { G = g; tilesPG = t; break; }
    }

    hipMemsetAsync(out_comb, 0, (size_t)TOKENS * HID * sizeof(float), stream);
    hipMemsetAsync(out_dm, 0, (size_t)TOKENS * NEXP * sizeof(float), stream);
    hipMemsetAsync(d_ws, 0, 256, stream);

    router_kernel<<<dim3(RT_BLOCKS), 512, 0, stream>>>(
        x, rw, rb, out_rw, out_dm, out_logits,
        counts, probsum, gatesum, lists, glists);
    finalize_kernel<<<1, 64, 0, stream>>>(counts, probsum, gatesum, poffs, out_aux);

    if (G > 0) {
        convx_kernel<<<dim3((TOKENS * HID / 4) / 256), 256, 0, stream>>>(x, Xb);
        convT_kernel<<<dim3(FFN_DIM / 32, HID / 64, NEXP), 256, 0, stream>>>(w1, W1T, HID, FFN_DIM);
        convT_kernel<<<dim3(HID / 32, FFN_DIM / 64, NEXP), 256, 0, stream>>>(w2, W2T, FFN_DIM, HID);
        for (int g = 0; g < G; ++g) {
            const int grBase = g * tilesPG * 128;
            gemm1_kernel<<<dim3(FFN_DIM / 128, tilesPG), 256, 0, stream>>>(
                Xb, W1T, b1, counts, poffs, lists, Hbuf, grBase);
            gemm2_kernel<<<dim3(HID / 128, tilesPG), 256, 0, stream>>>(
                Hbuf, W2T, b2, counts, poffs, lists, glists, out_comb, grBase);
        }
    } else {
        ffn_kernel<<<dim3(TOKENS / BM, NEXP), 256, 0, stream>>>(
            x, w1, b1, w2, b2, counts, lists, glists, out_comb);
    }
}

// Round 5
// 1008.324 us; speedup vs baseline: 19.3221x; 1.0462x over previous
//
#include <hip/hip_runtime.h>
#include <math.h>

#define TOKENS 16384
#define HID 768
#define FFN_DIM 3072
#define NEXP 8
#define MAX_TILES 264   // upper bound on padded 128-row tiles

#define RT_TPB 128      // router tokens per block
#define RT_BLOCKS (TOKENS / RT_TPB)

typedef __bf16 bf16x8 __attribute__((ext_vector_type(8)));
typedef float f32x4 __attribute__((ext_vector_type(4)));

#define GLOBAL_AS(p) ((const __attribute__((address_space(1))) void*)(p))
#define LDS_AS(p)    ((__attribute__((address_space(3))) void*)(p))

__device__ __forceinline__ float gelu_f(float x) {
    const float x3 = x * x * x;
    const float z = 0.7978845608028654f * (x + 0.044715f * x3);
    const float e = __expf(2.f * z);
    const float t = 1.f - 2.f / (e + 1.f);   // tanh(z)
    return 0.5f * x * (1.f + t);
}

__device__ __forceinline__ unsigned short f2bf(float v) {
    return __builtin_bit_cast(unsigned short, (__bf16)v);
}

// ---------------- router (block-aggregated atomics) ----------------
__global__ void __launch_bounds__(512) router_kernel(
    const float* __restrict__ x, const float* __restrict__ rw,
    const float* __restrict__ rb,
    float* __restrict__ out_rw, float* __restrict__ out_dm,
    float* __restrict__ out_logits,
    int* __restrict__ counts, float* __restrict__ probsum,
    float* __restrict__ gatesum, int* __restrict__ lists,
    float* __restrict__ glists)
{
    __shared__ int s_cnt[NEXP], s_base[NEXP];
    __shared__ float s_prob[NEXP], s_gate[NEXP];
    __shared__ int s_e1[RT_TPB], s_s1[RT_TPB], s_e2[RT_TPB], s_s2[RT_TPB];
    __shared__ float s_g1v[RT_TPB], s_g2v[RT_TPB];

    const int tid = threadIdx.x;
    if (tid < NEXP) { s_cnt[tid] = 0; s_prob[tid] = 0.f; s_gate[tid] = 0.f; }
    __syncthreads();

    const int wave = tid >> 6, lane = tid & 63;

    for (int it = 0; it < RT_TPB / 8; ++it) {   // 16 tokens per wave
        const int lt = wave * (RT_TPB / 8) + it;
        const int t = blockIdx.x * RT_TPB + lt;
        const float* xr = x + (size_t)t * HID;
        float acc[NEXP];
#pragma unroll
        for (int e = 0; e < NEXP; ++e) acc[e] = 0.f;
#pragma unroll
        for (int j = 0; j < 12; ++j) {
            const int i = lane + (j << 6);
            const float xv = xr[i];
            const float4 a = ((const float4*)(rw + (size_t)i * NEXP))[0];
            const float4 b = ((const float4*)(rw + (size_t)i * NEXP))[1];
            acc[0] += xv * a.x; acc[1] += xv * a.y; acc[2] += xv * a.z; acc[3] += xv * a.w;
            acc[4] += xv * b.x; acc[5] += xv * b.y; acc[6] += xv * b.z; acc[7] += xv * b.w;
        }
#pragma unroll
        for (int off = 32; off > 0; off >>= 1)
#pragma unroll
            for (int e = 0; e < NEXP; ++e) acc[e] += __shfl_down(acc[e], off, 64);

        if (lane == 0) {
            float lg[NEXP];
            float m = -1e30f;
#pragma unroll
            for (int e = 0; e < NEXP; ++e) { lg[e] = acc[e] + rb[e]; m = fmaxf(m, lg[e]); }
            float ex[NEXP]; float s = 0.f;
#pragma unroll
            for (int e = 0; e < NEXP; ++e) { ex[e] = expf(lg[e] - m); s += ex[e]; }
            const float inv = 1.f / s;
            float* lrow = out_logits + (size_t)t * NEXP;
            float* prow = out_rw + (size_t)t * NEXP;
#pragma unroll
            for (int e = 0; e < NEXP; ++e) {
                lrow[e] = lg[e];
                const float p = ex[e] * inv;
                prow[e] = p;
                atomicAdd(&s_prob[e], p);
            }
            int i1 = 0;
#pragma unroll
            for (int e = 1; e < NEXP; ++e) if (lg[e] > lg[i1]) i1 = e;
            int i2 = (i1 == 0) ? 1 : 0;
#pragma unroll
            for (int e = 0; e < NEXP; ++e) if (e != i1 && lg[e] > lg[i2]) i2 = e;
            const float e2 = expf(lg[i2] - lg[i1]);
            const float g1 = 1.f / (1.f + e2);
            const float g2 = e2 / (1.f + e2);
            out_dm[(size_t)t * NEXP + i1] = g1;
            out_dm[(size_t)t * NEXP + i2] = g2;
            atomicAdd(&s_gate[i1], g1);
            atomicAdd(&s_gate[i2], g2);
            s_e1[lt] = i1; s_s1[lt] = atomicAdd(&s_cnt[i1], 1); s_g1v[lt] = g1;
            s_e2[lt] = i2; s_s2[lt] = atomicAdd(&s_cnt[i2], 1); s_g2v[lt] = g2;
        }
    }
    __syncthreads();
    if (tid < NEXP) {
        s_base[tid] = atomicAdd(&counts[tid], s_cnt[tid]);
        atomicAdd(&probsum[tid], s_prob[tid]);
        atomicAdd(&gatesum[tid], s_gate[tid]);
    }
    __syncthreads();
    if (tid < RT_TPB) {
        const int t = blockIdx.x * RT_TPB + tid;
        int e = s_e1[tid]; int p = s_base[e] + s_s1[tid];
        lists[e * TOKENS + p] = t; glists[e * TOKENS + p] = s_g1v[tid];
        e = s_e2[tid]; p = s_base[e] + s_s2[tid];
        lists[e * TOKENS + p] = t; glists[e * TOKENS + p] = s_g2v[tid];
    }
}

// ---------------- finalize: aux loss + padded segment offsets ----------------
__global__ void finalize_kernel(const int* __restrict__ counts,
                                const float* __restrict__ probsum,
                                const float* __restrict__ gatesum,
                                int* __restrict__ poffs,
                                float* __restrict__ out_aux)
{
    if (threadIdx.x == 0 && blockIdx.x == 0) {
        float s = 0.f; int po = 0;
        for (int e = 0; e < NEXP; ++e) {
            poffs[e] = po;
            po += ((counts[e] + 127) >> 7) << 7;   // pad each segment to 128
            s += (probsum[e] / (float)TOKENS) * (gatesum[e] / (float)TOKENS);
        }
        poffs[NEXP] = po;
        *out_aux = s * (float)NEXP;
    }
}

// ---------------- gather X into segment order, fp32 -> bf16 ----------------
// one block per padded row; pad rows zeroed
__global__ void __launch_bounds__(192) gatherx_kernel(
    const float* __restrict__ x, const int* __restrict__ counts,
    const int* __restrict__ poffs, const int* __restrict__ lists,
    unsigned short* __restrict__ Xg)
{
    const int r = blockIdx.x;
    if (r >= poffs[NEXP]) return;
    int e = 0;
#pragma unroll
    for (int q = 1; q < NEXP; ++q) e += (r >= poffs[q]);
    const int ri = r - poffs[e];
    const int tid = threadIdx.x;
    uint2 o = make_uint2(0u, 0u);
    if (ri < counts[e]) {
        const int tok = lists[e * TOKENS + ri];
        const float4 v = *(const float4*)&x[(size_t)tok * HID + tid * 4];
        o.x = (unsigned)f2bf(v.x) | ((unsigned)f2bf(v.y) << 16);
        o.y = (unsigned)f2bf(v.z) | ((unsigned)f2bf(v.w) << 16);
    }
    *(uint2*)&Xg[(size_t)r * HID + tid * 4] = o;
}

// fp32 [E][R][C] -> bf16 transposed [E][C][R]
__global__ void __launch_bounds__(256) convT_kernel(const float* __restrict__ in,
                                                    unsigned short* __restrict__ out,
                                                    int R, int C)
{
    __shared__ float sT[32][65];
    const int e = blockIdx.z;
    const float* in_e = in + (size_t)e * R * C;
    unsigned short* out_e = out + (size_t)e * R * C;
    const int r0 = blockIdx.y * 64;
    const int c0 = blockIdx.x * 32;
    const int tid = threadIdx.x;
    const int rr = tid >> 3, c4 = (tid & 7) * 4;
#pragma unroll
    for (int half = 0; half < 2; ++half) {
        const int r = rr + half * 32;
        const float4 v = *(const float4*)&in_e[(size_t)(r0 + r) * C + c0 + c4];
        sT[c4 + 0][r] = v.x; sT[c4 + 1][r] = v.y;
        sT[c4 + 2][r] = v.z; sT[c4 + 3][r] = v.w;
    }
    __syncthreads();
    const int c = tid >> 3, u = tid & 7;
    uint4 pk;
    const float* sr = &sT[c][u * 8];
    pk.x = (unsigned)f2bf(sr[0]) | ((unsigned)f2bf(sr[1]) << 16);
    pk.y = (unsigned)f2bf(sr[2]) | ((unsigned)f2bf(sr[3]) << 16);
    pk.z = (unsigned)f2bf(sr[4]) | ((unsigned)f2bf(sr[5]) << 16);
    pk.w = (unsigned)f2bf(sr[6]) | ((unsigned)f2bf(sr[7]) << 16);
    *(uint4*)&out_e[(size_t)(c0 + c) * R + r0 + u * 8] = pk;
}

// ---------------- GEMM1: H = gelu(Xg @ W1 + b1), bf16 out ----------------
// grid: x = m-tile (padded to %8 for XCD affinity), y = n-tile
__global__ void __launch_bounds__(256) gemm1_kernel(
    const unsigned short* __restrict__ Xg, const unsigned short* __restrict__ W1T,
    const float* __restrict__ b1, const int* __restrict__ poffs,
    unsigned short* __restrict__ H, int grBase, int tilesPG)
{
    const int mtile = blockIdx.x;
    if (mtile >= tilesPG) return;
    const int gr = grBase + mtile * 128;
    if (gr >= poffs[NEXP]) return;
    int e = 0;
#pragma unroll
    for (int q = 1; q < NEXP; ++q) e += (gr >= poffs[q]);
    const int hbase = gr - grBase;
    const int n0 = blockIdx.y * 128;

    __shared__ __bf16 sA[128 * 64];
    __shared__ __bf16 sB[128 * 64];

    const int tid = threadIdx.x;
    const int w = tid >> 6, lane = tid & 63;

    const unsigned short* w1e = W1T + (size_t)e * (FFN_DIM * HID);
    const int lr = lane >> 3;
    const int lk = (lane & 7) * 8;
    const unsigned short* aPtr[4];
    const unsigned short* bPtr[4];
    __bf16* ldsA[4];
    __bf16* ldsB[4];
#pragma unroll
    for (int j = 0; j < 4; ++j) {
        const int row = (w * 4 + j) * 8 + lr;
        aPtr[j] = Xg + (size_t)(gr + row) * HID + lk;
        bPtr[j] = w1e + (size_t)(n0 + row) * HID + lk;
        ldsA[j] = sA + (w * 4 + j) * 512;
        ldsB[j] = sB + (w * 4 + j) * 512;
    }

    f32x4 acc[4][4];
#pragma unroll
    for (int a = 0; a < 4; ++a)
#pragma unroll
        for (int b = 0; b < 4; ++b) acc[a][b] = (f32x4)(0.f);

    const int wm = (w >> 1) * 64, wn = (w & 1) * 64;
    const int fr = lane & 15;
    const int fk = (lane >> 4) * 8;

    for (int kt = 0; kt < HID / 64; ++kt) {
        const int k0 = kt * 64;
#pragma unroll
        for (int j = 0; j < 4; ++j) {
            __builtin_amdgcn_global_load_lds(GLOBAL_AS(aPtr[j] + k0), LDS_AS(ldsA[j]), 16, 0, 0);
            __builtin_amdgcn_global_load_lds(GLOBAL_AS(bPtr[j] + k0), LDS_AS(ldsB[j]), 16, 0, 0);
        }
        __syncthreads();
#pragma unroll
        for (int kk = 0; kk < 64; kk += 32) {
            bf16x8 af[4], bb[4];
#pragma unroll
            for (int t = 0; t < 4; ++t) {
                af[t] = *(const bf16x8*)&sA[(wm + t * 16 + fr) * 64 + kk + fk];
                bb[t] = *(const bf16x8*)&sB[(wn + t * 16 + fr) * 64 + kk + fk];
            }
#pragma unroll
            for (int tm = 0; tm < 4; ++tm)
#pragma unroll
                for (int tn = 0; tn < 4; ++tn)
                    acc[tm][tn] = __builtin_amdgcn_mfma_f32_16x16x32_bf16(
                        af[tm], bb[tn], acc[tm][tn], 0, 0, 0);
        }
        __syncthreads();
    }

    const float* b1e = b1 + (size_t)e * FFN_DIM;
    float bias[4];
#pragma unroll
    for (int tn = 0; tn < 4; ++tn) bias[tn] = b1e[n0 + wn + tn * 16 + fr];
#pragma unroll
    for (int tm = 0; tm < 4; ++tm) {
#pragma unroll
        for (int tn = 0; tn < 4; ++tn) {
            const int n = n0 + wn + tn * 16 + fr;
#pragma unroll
            for (int r = 0; r < 4; ++r) {
                const int mloc = wm + tm * 16 + (lane >> 4) * 4 + r;
                const float h = gelu_f(acc[tm][tn][r] + bias[tn]);
                H[(size_t)(hbase + mloc) * FFN_DIM + n] = f2bf(h);
            }
        }
    }
}

// ---------------- GEMM2: out[tok] += gate*(H @ W2 + b2) ----------------
// grid: x = m-tile (padded to %8), y = n-tile
__global__ void __launch_bounds__(256) gemm2_kernel(
    const unsigned short* __restrict__ H, const unsigned short* __restrict__ W2T,
    const float* __restrict__ b2, const int* __restrict__ counts,
    const int* __restrict__ poffs, const int* __restrict__ lists,
    const float* __restrict__ glists, float* __restrict__ out,
    int grBase, int tilesPG)
{
    const int mtile = blockIdx.x;
    if (mtile >= tilesPG) return;
    const int gr = grBase + mtile * 128;
    if (gr >= poffs[NEXP]) return;
    int e = 0;
#pragma unroll
    for (int q = 1; q < NEXP; ++q) e += (gr >= poffs[q]);
    const int cnt = counts[e];
    const int m0 = gr - poffs[e];
    const int hbase = gr - grBase;
    const int n0 = blockIdx.y * 128;

    __shared__ __bf16 sA[128 * 64];
    __shared__ __bf16 sB[128 * 64];
    __shared__ int sTok[128];
    __shared__ float sGate[128];

    const int tid = threadIdx.x;
    const int w = tid >> 6, lane = tid & 63;
    if (tid < 128) {
        int ri = m0 + tid; if (ri > cnt - 1) ri = cnt - 1;
        sTok[tid] = lists[e * TOKENS + ri];
        sGate[tid] = glists[e * TOKENS + ri];
    }

    const unsigned short* w2e = W2T + (size_t)e * (FFN_DIM * HID);
    const int lr = lane >> 3;
    const int lk = (lane & 7) * 8;
    const unsigned short* aPtr[4];
    const unsigned short* bPtr[4];
    __bf16* ldsA[4];
    __bf16* ldsB[4];
#pragma unroll
    for (int j = 0; j < 4; ++j) {
        const int row = (w * 4 + j) * 8 + lr;
        aPtr[j] = H + (size_t)(hbase + row) * FFN_DIM + lk;
        bPtr[j] = w2e + (size_t)(n0 + row) * FFN_DIM + lk;
        ldsA[j] = sA + (w * 4 + j) * 512;
        ldsB[j] = sB + (w * 4 + j) * 512;
    }

    f32x4 acc[4][4];
#pragma unroll
    for (int a = 0; a < 4; ++a)
#pragma unroll
        for (int b = 0; b < 4; ++b) acc[a][b] = (f32x4)(0.f);

    const int wm = (w >> 1) * 64, wn = (w & 1) * 64;
    const int fr = lane & 15;
    const int fk = (lane >> 4) * 8;

    for (int kt = 0; kt < FFN_DIM / 64; ++kt) {
        const int k0 = kt * 64;
#pragma unroll
        for (int j = 0; j < 4; ++j) {
            __builtin_amdgcn_global_load_lds(GLOBAL_AS(aPtr[j] + k0), LDS_AS(ldsA[j]), 16, 0, 0);
            __builtin_amdgcn_global_load_lds(GLOBAL_AS(bPtr[j] + k0), LDS_AS(ldsB[j]), 16, 0, 0);
        }
        __syncthreads();
#pragma unroll
        for (int kk = 0; kk < 64; kk += 32) {
            bf16x8 af[4], bb[4];
#pragma unroll
            for (int t = 0; t < 4; ++t) {
                af[t] = *(const bf16x8*)&sA[(wm + t * 16 + fr) * 64 + kk + fk];
                bb[t] = *(const bf16x8*)&sB[(wn + t * 16 + fr) * 64 + kk + fk];
            }
#pragma unroll
            for (int tm = 0; tm < 4; ++tm)
#pragma unroll
                for (int tn = 0; tn < 4; ++tn)
                    acc[tm][tn] = __builtin_amdgcn_mfma_f32_16x16x32_bf16(
                        af[tm], bb[tn], acc[tm][tn], 0, 0, 0);
        }
        __syncthreads();
    }

    const float* b2e = b2 + (size_t)e * HID;
    float bias[4];
#pragma unroll
    for (int tn = 0; tn < 4; ++tn) bias[tn] = b2e[n0 + wn + tn * 16 + fr];
#pragma unroll
    for (int tm = 0; tm < 4; ++tm) {
#pragma unroll
        for (int tn = 0; tn < 4; ++tn) {
            const int n = n0 + wn + tn * 16 + fr;
#pragma unroll
            for (int r = 0; r < 4; ++r) {
                const int mloc = wm + tm * 16 + (lane >> 4) * 4 + r;
                if (m0 + mloc < cnt) {
                    const float y = acc[tm][tn][r] + bias[tn];
                    atomicAdd(&out[(size_t)sTok[mloc] * HID + n], sGate[mloc] * y);
                }
            }
        }
    }
}

// ---------------- fallback fp32 FFN (ws too small) ----------------
#define BM 16
#define KC 64
#define XS 772
#define HS 68
__global__ void __launch_bounds__(256) ffn_kernel(
    const float* __restrict__ x, const float* __restrict__ w1,
    const float* __restrict__ b1, const float* __restrict__ w2,
    const float* __restrict__ b2, const int* __restrict__ counts,
    const int* __restrict__ lists, const float* __restrict__ glists,
    float* __restrict__ out)
{
    const int e = blockIdx.y;
    const int count = counts[e];
    const int row0 = blockIdx.x * BM;
    if (row0 >= count) return;

    __shared__ float sX[BM * XS];
    __shared__ float sH[BM * HS];
    __shared__ int sTokF[BM];
    __shared__ float sGateF[BM];
    const int tid = threadIdx.x;

    if (tid < BM) {
        const int ri = row0 + tid;
        int tok = 0; float g = 0.f;
        if (ri < count) { tok = lists[e * TOKENS + ri]; g = glists[e * TOKENS + ri]; }
        sTokF[tid] = tok; sGateF[tid] = g;
    }
    __syncthreads();
    {
        const int r = tid >> 4, q = tid & 15;
        const float4* src = (const float4*)(x + (size_t)sTokF[r] * HID);
#pragma unroll
        for (int j = 0; j < 12; ++j) {
            const float4 v = src[q + (j << 4)];
            *(float4*)&sX[r * XS + ((q + (j << 4)) << 2)] = v;
        }
    }
    __syncthreads();

    const float* w1e = w1 + (size_t)e * HID * FFN_DIM;
    const float* w2e = w2 + (size_t)e * FFN_DIM * HID;
    const float* b1e = b1 + (size_t)e * FFN_DIM;
    const float* b2e = b2 + (size_t)e * HID;
    const int r1 = tid & 15;
    const int c0 = (tid >> 4) << 2;
    const int c2 = (tid >> 4) * 48;

    float Y[48];
#pragma unroll
    for (int j = 0; j < 48; ++j) Y[j] = 0.f;

    for (int ch = 0; ch < FFN_DIM / KC; ++ch) {
        float h0 = 0.f, h1 = 0.f, h2 = 0.f, h3 = 0.f;
        const float* w1c = w1e + ch * KC + c0;
        for (int i = 0; i < HID; i += 4) {
            const float4 xv = *(const float4*)&sX[r1 * XS + i];
            const float* wp = w1c + (size_t)i * FFN_DIM;
            const float4 wa = *(const float4*)(wp);
            const float4 wb = *(const float4*)(wp + FFN_DIM);
            const float4 wc = *(const float4*)(wp + 2 * FFN_DIM);
            const float4 wd = *(const float4*)(wp + 3 * FFN_DIM);
            h0 += xv.x * wa.x + xv.y * wb.x + xv.z * wc.x + xv.w * wd.x;
            h1 += xv.x * wa.y + xv.y * wb.y + xv.z * wc.y + xv.w * wd.y;
            h2 += xv.x * wa.z + xv.y * wb.z + xv.z * wc.z + xv.w * wd.z;
            h3 += xv.x * wa.w + xv.y * wb.w + xv.z * wc.w + xv.w * wd.w;
        }
        const int cb = ch * KC + c0;
        h0 = gelu_f(h0 + b1e[cb + 0]);
        h1 = gelu_f(h1 + b1e[cb + 1]);
        h2 = gelu_f(h2 + b1e[cb + 2]);
        h3 = gelu_f(h3 + b1e[cb + 3]);
        __syncthreads();
        *(float4*)&sH[r1 * HS + c0] = make_float4(h0, h1, h2, h3);
        __syncthreads();
        const float* w2c = w2e + (size_t)ch * KC * HID + c2;
        for (int k = 0; k < KC; ++k) {
            const float hv = sH[r1 * HS + k];
            const float4* wr = (const float4*)(w2c + (size_t)k * HID);
#pragma unroll
            for (int j4 = 0; j4 < 12; ++j4) {
                const float4 wv = wr[j4];
                Y[j4 * 4 + 0] += hv * wv.x;
                Y[j4 * 4 + 1] += hv * wv.y;
                Y[j4 * 4 + 2] += hv * wv.z;
                Y[j4 * 4 + 3] += hv * wv.w;
            }
        }
    }
    const int ri = row0 + r1;
    if (ri < count) {
        const float g = sGateF[r1];
        float* orow = out + (size_t)sTokF[r1] * HID + c2;
#pragma unroll
        for (int j = 0; j < 48; ++j)
            atomicAdd(&orow[j], g * (Y[j] + b2e[c2 + j]));
    }
}

extern "C" void kernel_launch(void* const* d_in, const int* in_sizes, int n_in,
                              void* d_out, int out_size, void* d_ws, size_t ws_size,
                              hipStream_t stream)
{
    const float* x  = (const float*)d_in[0];
    const float* rw = (const float*)d_in[1];
    const float* rb = (const float*)d_in[2];
    const float* w1 = (const float*)d_in[3];
    const float* b1 = (const float*)d_in[4];
    const float* w2 = (const float*)d_in[5];
    const float* b2 = (const float*)d_in[6];

    float* out = (float*)d_out;
    float* out_comb   = out;
    float* out_rw     = out + (size_t)TOKENS * HID;
    float* out_dm     = out_rw + (size_t)TOKENS * NEXP;
    float* out_aux    = out_dm + (size_t)TOKENS * NEXP;
    float* out_logits = out_aux + 1;

    char* ws = (char*)d_ws;
    int*   counts  = (int*)ws;
    int*   poffs   = (int*)(ws + 64);
    float* probsum = (float*)(ws + 128);
    float* gatesum = (float*)(ws + 160);
    int*   lists   = (int*)(ws + 256);
    float* glists  = (float*)(ws + 256 + (size_t)NEXP * TOKENS * 4);
    size_t off = 256 + (size_t)NEXP * TOKENS * 8;
    off = (off + 255) & ~(size_t)255;
    unsigned short* Xg  = (unsigned short*)(ws + off); off += (size_t)MAX_TILES * 128 * HID * 2;
    unsigned short* W1T = (unsigned short*)(ws + off); off += (size_t)NEXP * HID * FFN_DIM * 2;
    unsigned short* W2T = (unsigned short*)(ws + off); off += (size_t)NEXP * HID * FFN_DIM * 2;
    unsigned short* Hbuf = (unsigned short*)(ws + off);
    const size_t fixed = off;

    int G = -1, tilesPG = 0;
    const int cand[6] = {1, 2, 4, 8, 16, 32};
    for (int ci = 0; ci < 6; ++ci) {
        const int g = cand[ci];
        const int t = (MAX_TILES + g - 1) / g;
        const size_t need = fixed + (size_t)t * 128 * FFN_DIM * 2;
        if (need <= ws_size) { G = g; tilesPG = t; break; }
    }

    hipMemsetAsync(out_comb, 0, (size_t)TOKENS * HID * sizeof(float), stream);
    hipMemsetAsync(out_dm, 0, (size_t)TOKENS * NEXP * sizeof(float), stream);
    hipMemsetAsync(d_ws, 0, 256, stream);

    router_kernel<<<dim3(RT_BLOCKS), 512, 0, stream>>>(
        x, rw, rb, out_rw, out_dm, out_logits,
        counts, probsum, gatesum, lists, glists);
    finalize_kernel<<<1, 64, 0, stream>>>(counts, probsum, gatesum, poffs, out_aux);

    if (G > 0) {
        gatherx_kernel<<<dim3(MAX_TILES * 128), 192, 0, stream>>>(
            x, counts, poffs, lists, Xg);
        convT_kernel<<<dim3(FFN_DIM / 32, HID / 64, NEXP), 256, 0, stream>>>(w1, W1T, HID, FFN_DIM);
        convT_kernel<<<dim3(HID / 32, FFN_DIM / 64, NEXP), 256, 0, stream>>>(w2, W2T, FFN_DIM, HID);
        const int mtPad = (tilesPG + 7) & ~7;   // %8 pad -> block id % 8 == mtile % 8 (XCD affinity)
        for (int g = 0; g < G; ++g) {
            const int grBase = g * tilesPG * 128;
            gemm1_kernel<<<dim3(mtPad, FFN_DIM / 128), 256, 0, stream>>>(
                Xg, W1T, b1, poffs, Hbuf, grBase, tilesPG);
            gemm2_kernel<<<dim3(mtPad, HID / 128), 256, 0, stream>>>(
                Hbuf, W2T, b2, counts, poffs, lists, glists, out_comb, grBase, tilesPG);
        }
    } else {
        ffn_kernel<<<dim3(TOKENS / BM, NEXP), 256, 0, stream>>>(
            x, w1, b1, w2, b2, counts, lists, glists, out_comb);
    }
}